// Round 1
// baseline (552.316 us; speedup 1.0000x reference)
//
#include <hip/hip_runtime.h>
#include <math.h>

#define NNODES 50000
#define NEDGES 800000

// ---------------- CSR construction ----------------

__global__ void zero_i32(int* __restrict__ p, int n) {
    int i = blockIdx.x * 256 + threadIdx.x;
    if (i < n) p[i] = 0;
}

__global__ void hist_kernel(const int* __restrict__ dst, int* __restrict__ counts, int e) {
    int i = blockIdx.x * 256 + threadIdx.x;
    if (i < e) atomicAdd(&counts[dst[i]], 1);
}

// inclusive scan per 256-block, writes row_ptr[i+1], block sums out
__global__ void scan1_kernel(const int* __restrict__ counts, int* __restrict__ row_ptr,
                             int* __restrict__ bsums, int n) {
    __shared__ int s[256];
    int tid = threadIdx.x;
    int i = blockIdx.x * 256 + tid;
    int v = (i < n) ? counts[i] : 0;
    s[tid] = v;
    __syncthreads();
    #pragma unroll
    for (int o = 1; o < 256; o <<= 1) {
        int t = (tid >= o) ? s[tid - o] : 0;
        __syncthreads();
        s[tid] += t;
        __syncthreads();
    }
    if (i < n) row_ptr[i + 1] = s[tid];
    if (tid == 255) bsums[blockIdx.x] = s[255];
}

// exclusive scan of block sums (nb <= 256), in place
__global__ void scan2_kernel(int* __restrict__ bsums, int nb) {
    __shared__ int s[256];
    int tid = threadIdx.x;
    int v = (tid < nb) ? bsums[tid] : 0;
    s[tid] = v;
    __syncthreads();
    #pragma unroll
    for (int o = 1; o < 256; o <<= 1) {
        int t = (tid >= o) ? s[tid - o] : 0;
        __syncthreads();
        s[tid] += t;
        __syncthreads();
    }
    if (tid < nb) bsums[tid] = s[tid] - v;  // exclusive
}

__global__ void scan3_kernel(int* __restrict__ row_ptr, const int* __restrict__ bsums, int n) {
    int i = blockIdx.x * 256 + threadIdx.x;
    if (i < n) row_ptr[i + 1] += bsums[blockIdx.x];
    if (i == 0) row_ptr[0] = 0;
}

__global__ void fill_kernel(const int* __restrict__ src, const int* __restrict__ dst,
                            const int* __restrict__ row_ptr, int* __restrict__ cursor,
                            int* __restrict__ csr_src, int e) {
    int i = blockIdx.x * 256 + threadIdx.x;
    if (i < e) {
        int d = dst[i];
        int pos = atomicAdd(&cursor[d], 1);
        csr_src[row_ptr[d] + pos] = src[i];
    }
}

// ---------------- GEMM: H[n][M] = A[n][128] @ W[128][M] ----------------
// block 256, tile 64 rows x 128 cols, BK=32

__global__ __launch_bounds__(256) void gemm_kernel(const float* __restrict__ A,
                                                   const float* __restrict__ W,
                                                   float* __restrict__ H, int n, int M) {
    __shared__ float As[32][65];   // [kk][row], padded
    __shared__ float Bs[32][128];  // [kk][col]
    int tid = threadIdx.x;
    int tr = tid >> 4;       // 0..15
    int tc = tid & 15;       // 0..15
    int row0 = blockIdx.x * 64;
    int col0 = blockIdx.y * 128;
    float acc[4][8];
    #pragma unroll
    for (int r = 0; r < 4; ++r)
        #pragma unroll
        for (int j = 0; j < 8; ++j) acc[r][j] = 0.f;

    for (int k0 = 0; k0 < 128; k0 += 32) {
        // A tile: 64x32
        #pragma unroll
        for (int i = 0; i < 8; ++i) {
            int flat = tid + i * 256;
            int r = flat >> 5, kk = flat & 31;
            int gr = row0 + r;
            As[kk][r] = (gr < n) ? A[(size_t)gr * 128 + k0 + kk] : 0.f;
        }
        // B tile: 32x128
        #pragma unroll
        for (int i = 0; i < 16; ++i) {
            int flat = tid + i * 256;
            int kk = flat >> 7, j = flat & 127;
            Bs[kk][j] = W[(size_t)(k0 + kk) * M + col0 + j];
        }
        __syncthreads();
        #pragma unroll
        for (int kk = 0; kk < 32; ++kk) {
            float a0 = As[kk][tr * 4 + 0];
            float a1 = As[kk][tr * 4 + 1];
            float a2 = As[kk][tr * 4 + 2];
            float a3 = As[kk][tr * 4 + 3];
            float4 b0 = *(const float4*)&Bs[kk][tc * 8];
            float4 b1 = *(const float4*)&Bs[kk][tc * 8 + 4];
            float bb[8] = {b0.x, b0.y, b0.z, b0.w, b1.x, b1.y, b1.z, b1.w};
            #pragma unroll
            for (int j = 0; j < 8; ++j) {
                acc[0][j] += a0 * bb[j];
                acc[1][j] += a1 * bb[j];
                acc[2][j] += a2 * bb[j];
                acc[3][j] += a3 * bb[j];
            }
        }
        __syncthreads();
    }
    #pragma unroll
    for (int r = 0; r < 4; ++r) {
        int gr = row0 + tr * 4 + r;
        if (gr < n) {
            float4 o0 = {acc[r][0], acc[r][1], acc[r][2], acc[r][3]};
            float4 o1 = {acc[r][4], acc[r][5], acc[r][6], acc[r][7]};
            *(float4*)&H[(size_t)gr * M + col0 + tc * 8] = o0;
            *(float4*)&H[(size_t)gr * M + col0 + tc * 8 + 4] = o1;
        }
    }
}

// ---------------- per-node attention logits ----------------
// one wave per node; lane l handles channels l*CPL .. l*CPL+CPL-1; head = l>>4

template <int CPL>
__global__ __launch_bounds__(256) void alpha_kernel(const float* __restrict__ h,
                                                    const float* __restrict__ a_src,
                                                    const float* __restrict__ a_dst,
                                                    float* __restrict__ asrc,
                                                    float* __restrict__ adst, int n) {
    const int TOTC = 64 * CPL;
    const int CH = TOTC / 4;
    int lane = threadIdx.x & 63;
    int node = blockIdx.x * 4 + (threadIdx.x >> 6);
    if (node >= n) return;
    int head = lane >> 4;
    int c0 = lane * CPL;
    int cih0 = c0 - head * CH;
    float ss = 0.f, sd = 0.f;
    const float* hp = h + (size_t)node * TOTC + c0;
    #pragma unroll
    for (int q = 0; q < CPL; ++q) {
        float v = hp[q];
        ss += v * a_src[head * CH + cih0 + q];
        sd += v * a_dst[head * CH + cih0 + q];
    }
    #pragma unroll
    for (int o = 1; o < 16; o <<= 1) {
        ss += __shfl_xor(ss, o);
        sd += __shfl_xor(sd, o);
    }
    if ((lane & 15) == 0) {
        asrc[node * 4 + head] = ss;
        adst[node * 4 + head] = sd;
    }
}

// ---------------- segment softmax + weighted aggregation ----------------
// one wave per dst node. Lane l owns channels l*CPL..l*CPL+CPL-1 (head = l>>4).

template <int CPL, bool MEAN>
__global__ __launch_bounds__(256) void aggregate_kernel(
    const float* __restrict__ h, const float* __restrict__ asrc,
    const float* __restrict__ adst, const int* __restrict__ csr_src,
    const int* __restrict__ row_ptr, const float* __restrict__ bias,
    float* __restrict__ out, int n) {
    const int TOTC = 64 * CPL;
    int lane = threadIdx.x & 63;
    int node = blockIdx.x * 4 + (threadIdx.x >> 6);
    if (node >= n) return;
    int start = row_ptr[node];
    int end = row_ptr[node + 1];

    float ad0 = adst[node * 4 + 0];
    float ad1 = adst[node * 4 + 1];
    float ad2 = adst[node * 4 + 2];
    float ad3 = adst[node * 4 + 3];

    // pass 1: segment max per head
    float m0 = -INFINITY, m1 = -INFINITY, m2 = -INFINITY, m3 = -INFINITY;
    for (int i = start + lane; i < end; i += 64) {
        int s = csr_src[i];
        const float* ap = asrc + (size_t)s * 4;
        float e0 = ap[0] + ad0; e0 = (e0 > 0.f) ? e0 : 0.2f * e0; m0 = fmaxf(m0, e0);
        float e1 = ap[1] + ad1; e1 = (e1 > 0.f) ? e1 : 0.2f * e1; m1 = fmaxf(m1, e1);
        float e2 = ap[2] + ad2; e2 = (e2 > 0.f) ? e2 : 0.2f * e2; m2 = fmaxf(m2, e2);
        float e3 = ap[3] + ad3; e3 = (e3 > 0.f) ? e3 : 0.2f * e3; m3 = fmaxf(m3, e3);
    }
    #pragma unroll
    for (int o = 32; o; o >>= 1) {
        m0 = fmaxf(m0, __shfl_xor(m0, o));
        m1 = fmaxf(m1, __shfl_xor(m1, o));
        m2 = fmaxf(m2, __shfl_xor(m2, o));
        m3 = fmaxf(m3, __shfl_xor(m3, o));
    }

    // pass 2: accumulate unnormalized p * h[src] and p-sums
    float acc[CPL];
    #pragma unroll
    for (int q = 0; q < CPL; ++q) acc[q] = 0.f;
    float ps0 = 0.f, ps1 = 0.f, ps2 = 0.f, ps3 = 0.f;

    for (int base = start; base < end; base += 64) {
        int cnt = end - base;
        if (cnt > 64) cnt = 64;
        int s = 0;
        float p0 = 0.f, p1 = 0.f, p2 = 0.f, p3 = 0.f;
        if (lane < cnt) {
            s = csr_src[base + lane];
            const float* ap = asrc + (size_t)s * 4;
            float e0 = ap[0] + ad0; e0 = (e0 > 0.f) ? e0 : 0.2f * e0; p0 = expf(e0 - m0);
            float e1 = ap[1] + ad1; e1 = (e1 > 0.f) ? e1 : 0.2f * e1; p1 = expf(e1 - m1);
            float e2 = ap[2] + ad2; e2 = (e2 > 0.f) ? e2 : 0.2f * e2; p2 = expf(e2 - m2);
            float e3 = ap[3] + ad3; e3 = (e3 > 0.f) ? e3 : 0.2f * e3; p3 = expf(e3 - m3);
            ps0 += p0; ps1 += p1; ps2 += p2; ps3 += p3;
        }
        for (int j = 0; j < cnt; ++j) {
            int sj = __shfl(s, j);
            float w0 = __shfl(p0, j);
            float w1 = __shfl(p1, j);
            float w2 = __shfl(p2, j);
            float w3 = __shfl(p3, j);
            float wlo = (lane & 16) ? w1 : w0;
            float whi = (lane & 16) ? w3 : w2;
            float w = (lane & 32) ? whi : wlo;
            const float* hr = h + (size_t)sj * TOTC + lane * CPL;
            if constexpr (CPL == 2) {
                float2 v = *(const float2*)hr;
                acc[0] += w * v.x;
                acc[1] += w * v.y;
            } else {
                float4 v = *(const float4*)hr;
                acc[0] += w * v.x;
                acc[1] += w * v.y;
                acc[2] += w * v.z;
                acc[3] += w * v.w;
            }
        }
    }
    #pragma unroll
    for (int o = 32; o; o >>= 1) {
        ps0 += __shfl_xor(ps0, o);
        ps1 += __shfl_xor(ps1, o);
        ps2 += __shfl_xor(ps2, o);
        ps3 += __shfl_xor(ps3, o);
    }
    float plo = (lane & 16) ? ps1 : ps0;
    float phi = (lane & 16) ? ps3 : ps2;
    float pown = ((lane & 32) ? phi : plo) + 1e-16f;

    if constexpr (!MEAN) {
        // concat output: [n][TOTC], channel c = lane*CPL+q
        if constexpr (CPL == 2) {
            float2 o2;
            o2.x = acc[0] / pown + bias[lane * 2 + 0];
            o2.y = acc[1] / pown + bias[lane * 2 + 1];
            *(float2*)&out[(size_t)node * 128 + lane * 2] = o2;
        } else {
            float4 o4;
            o4.x = acc[0] / pown + bias[lane * 4 + 0];
            o4.y = acc[1] / pown + bias[lane * 4 + 1];
            o4.z = acc[2] / pown + bias[lane * 4 + 2];
            o4.w = acc[3] / pown + bias[lane * 4 + 3];
            *(float4*)&out[(size_t)node * 256 + lane * 4] = o4;
        }
    } else {
        // CPL==4: mean over heads. lane l holds head l>>4, cih = 4*(l&15)+q
        float r0 = acc[0] / pown;
        float r1 = acc[1] / pown;
        float r2 = acc[2] / pown;
        float r3 = acc[3] / pown;
        #pragma unroll
        for (int o = 16; o <= 32; o <<= 1) {
            r0 += __shfl_xor(r0, o);
            r1 += __shfl_xor(r1, o);
            r2 += __shfl_xor(r2, o);
            r3 += __shfl_xor(r3, o);
        }
        if (lane < 16) {
            float4 o4;
            o4.x = 0.25f * r0 + bias[lane * 4 + 0];
            o4.y = 0.25f * r1 + bias[lane * 4 + 1];
            o4.z = 0.25f * r2 + bias[lane * 4 + 2];
            o4.w = 0.25f * r3 + bias[lane * 4 + 3];
            *(float4*)&out[(size_t)node * 64 + lane * 4] = o4;
        }
    }
}

// ---------------- launch ----------------

extern "C" void kernel_launch(void* const* d_in, const int* in_sizes, int n_in,
                              void* d_out, int out_size, void* d_ws, size_t ws_size,
                              hipStream_t stream) {
    const float* x = (const float*)d_in[0];
    const int* ei = (const int*)d_in[1];
    const int* src = ei;
    const int* dst = ei + NEDGES;
    const float* W1 = (const float*)d_in[2];
    const float* as1 = (const float*)d_in[3];
    const float* ad1 = (const float*)d_in[4];
    const float* b1 = (const float*)d_in[5];
    const float* W2 = (const float*)d_in[6];
    const float* as2 = (const float*)d_in[7];
    const float* ad2 = (const float*)d_in[8];
    const float* b2 = (const float*)d_in[9];
    const float* W3 = (const float*)d_in[10];
    const float* as3 = (const float*)d_in[11];
    const float* ad3 = (const float*)d_in[12];
    const float* b3 = (const float*)d_in[13];

    char* ws = (char*)d_ws;
    size_t off = 0;
    auto take = [&](size_t bytes) -> char* {
        char* p = ws + off;
        off = (off + bytes + 255) & ~(size_t)255;
        return p;
    };
    int* csr = (int*)take((size_t)NEDGES * 4);
    int* row_ptr = (int*)take((size_t)(NNODES + 1) * 4);
    int* counts = (int*)take((size_t)NNODES * 4);
    int* cursor = (int*)take((size_t)NNODES * 4);
    int* bsums = (int*)take(1024 * 4);
    float* asrc = (float*)take((size_t)NNODES * 4 * 4);
    float* adst = (float*)take((size_t)NNODES * 4 * 4);
    float* hbuf = (float*)take((size_t)NNODES * 256 * 4);
    float* buf1 = (float*)take((size_t)NNODES * 128 * 4);
    float* outp = (float*)d_out;

    int nbN = (NNODES + 255) / 256;   // 196
    int nbE = (NEDGES + 255) / 256;   // 3125
    int gnode4 = (NNODES + 3) / 4;    // 12500

    // CSR build (once; same graph for all layers)
    zero_i32<<<nbN, 256, 0, stream>>>(counts, NNODES);
    hist_kernel<<<nbE, 256, 0, stream>>>(dst, counts, NEDGES);
    scan1_kernel<<<nbN, 256, 0, stream>>>(counts, row_ptr, bsums, NNODES);
    scan2_kernel<<<1, 256, 0, stream>>>(bsums, nbN);
    scan3_kernel<<<nbN, 256, 0, stream>>>(row_ptr, bsums, NNODES);
    zero_i32<<<nbN, 256, 0, stream>>>(cursor, NNODES);
    fill_kernel<<<nbE, 256, 0, stream>>>(src, dst, row_ptr, cursor, csr, NEDGES);

    dim3 g128((NNODES + 63) / 64, 1);
    dim3 g256((NNODES + 63) / 64, 2);

    // layer 1: x[50000][128] -> buf1[50000][128]
    gemm_kernel<<<g128, 256, 0, stream>>>(x, W1, hbuf, NNODES, 128);
    alpha_kernel<2><<<gnode4, 256, 0, stream>>>(hbuf, as1, ad1, asrc, adst, NNODES);
    aggregate_kernel<2, false><<<gnode4, 256, 0, stream>>>(hbuf, asrc, adst, csr, row_ptr, b1, buf1, NNODES);

    // layer 2: buf1 -> buf1 (in place; GEMM consumed it first)
    gemm_kernel<<<g128, 256, 0, stream>>>(buf1, W2, hbuf, NNODES, 128);
    alpha_kernel<2><<<gnode4, 256, 0, stream>>>(hbuf, as2, ad2, asrc, adst, NNODES);
    aggregate_kernel<2, false><<<gnode4, 256, 0, stream>>>(hbuf, asrc, adst, csr, row_ptr, b2, buf1, NNODES);

    // layer 3: buf1 -> out (mean over heads)
    gemm_kernel<<<g256, 256, 0, stream>>>(buf1, W3, hbuf, NNODES, 256);
    alpha_kernel<4><<<gnode4, 256, 0, stream>>>(hbuf, as3, ad3, asrc, adst, NNODES);
    aggregate_kernel<4, true><<<gnode4, 256, 0, stream>>>(hbuf, asrc, adst, csr, row_ptr, b3, outp, NNODES);
}

// Round 2
// 515.099 us; speedup vs baseline: 1.0723x; 1.0723x over previous
//
#include <hip/hip_runtime.h>
#include <math.h>

#define NNODES 50000
#define NEDGES 800000

// ---------------- CSR construction ----------------

__global__ void zero_i32(int* __restrict__ p, int n) {
    int i = blockIdx.x * 256 + threadIdx.x;
    if (i < n) p[i] = 0;
}

__global__ void hist_kernel(const int* __restrict__ dst, int* __restrict__ counts, int e) {
    int i = blockIdx.x * 256 + threadIdx.x;
    if (i < e) atomicAdd(&counts[dst[i]], 1);
}

__global__ void scan1_kernel(const int* __restrict__ counts, int* __restrict__ row_ptr,
                             int* __restrict__ bsums, int n) {
    __shared__ int s[256];
    int tid = threadIdx.x;
    int i = blockIdx.x * 256 + tid;
    int v = (i < n) ? counts[i] : 0;
    s[tid] = v;
    __syncthreads();
    #pragma unroll
    for (int o = 1; o < 256; o <<= 1) {
        int t = (tid >= o) ? s[tid - o] : 0;
        __syncthreads();
        s[tid] += t;
        __syncthreads();
    }
    if (i < n) row_ptr[i + 1] = s[tid];
    if (tid == 255) bsums[blockIdx.x] = s[255];
}

__global__ void scan2_kernel(int* __restrict__ bsums, int nb) {
    __shared__ int s[256];
    int tid = threadIdx.x;
    int v = (tid < nb) ? bsums[tid] : 0;
    s[tid] = v;
    __syncthreads();
    #pragma unroll
    for (int o = 1; o < 256; o <<= 1) {
        int t = (tid >= o) ? s[tid - o] : 0;
        __syncthreads();
        s[tid] += t;
        __syncthreads();
    }
    if (tid < nb) bsums[tid] = s[tid] - v;  // exclusive
}

__global__ void scan3_kernel(int* __restrict__ row_ptr, const int* __restrict__ bsums, int n) {
    int i = blockIdx.x * 256 + threadIdx.x;
    if (i < n) row_ptr[i + 1] += bsums[blockIdx.x];
    if (i == 0) row_ptr[0] = 0;
}

__global__ void fill_kernel(const int* __restrict__ src, const int* __restrict__ dst,
                            const int* __restrict__ row_ptr, int* __restrict__ cursor,
                            int* __restrict__ csr_src, int e) {
    int i = blockIdx.x * 256 + threadIdx.x;
    if (i < e) {
        int d = dst[i];
        int pos = atomicAdd(&cursor[d], 1);
        csr_src[row_ptr[d] + pos] = src[i];
    }
}

// ---------------- GEMM: H[n][M] = A[n][128] @ W[128][M] ----------------

__global__ __launch_bounds__(256) void gemm_kernel(const float* __restrict__ A,
                                                   const float* __restrict__ W,
                                                   float* __restrict__ H, int n, int M) {
    __shared__ float As[32][65];
    __shared__ float Bs[32][128];
    int tid = threadIdx.x;
    int tr = tid >> 4;
    int tc = tid & 15;
    int row0 = blockIdx.x * 64;
    int col0 = blockIdx.y * 128;
    float acc[4][8];
    #pragma unroll
    for (int r = 0; r < 4; ++r)
        #pragma unroll
        for (int j = 0; j < 8; ++j) acc[r][j] = 0.f;

    for (int k0 = 0; k0 < 128; k0 += 32) {
        #pragma unroll
        for (int i = 0; i < 8; ++i) {
            int flat = tid + i * 256;
            int r = flat >> 5, kk = flat & 31;
            int gr = row0 + r;
            As[kk][r] = (gr < n) ? A[(size_t)gr * 128 + k0 + kk] : 0.f;
        }
        #pragma unroll
        for (int i = 0; i < 16; ++i) {
            int flat = tid + i * 256;
            int kk = flat >> 7, j = flat & 127;
            Bs[kk][j] = W[(size_t)(k0 + kk) * M + col0 + j];
        }
        __syncthreads();
        #pragma unroll
        for (int kk = 0; kk < 32; ++kk) {
            float a0 = As[kk][tr * 4 + 0];
            float a1 = As[kk][tr * 4 + 1];
            float a2 = As[kk][tr * 4 + 2];
            float a3 = As[kk][tr * 4 + 3];
            float4 b0 = *(const float4*)&Bs[kk][tc * 8];
            float4 b1 = *(const float4*)&Bs[kk][tc * 8 + 4];
            float bb[8] = {b0.x, b0.y, b0.z, b0.w, b1.x, b1.y, b1.z, b1.w};
            #pragma unroll
            for (int j = 0; j < 8; ++j) {
                acc[0][j] += a0 * bb[j];
                acc[1][j] += a1 * bb[j];
                acc[2][j] += a2 * bb[j];
                acc[3][j] += a3 * bb[j];
            }
        }
        __syncthreads();
    }
    #pragma unroll
    for (int r = 0; r < 4; ++r) {
        int gr = row0 + tr * 4 + r;
        if (gr < n) {
            float4 o0 = {acc[r][0], acc[r][1], acc[r][2], acc[r][3]};
            float4 o1 = {acc[r][4], acc[r][5], acc[r][6], acc[r][7]};
            *(float4*)&H[(size_t)gr * M + col0 + tc * 8] = o0;
            *(float4*)&H[(size_t)gr * M + col0 + tc * 8 + 4] = o1;
        }
    }
}

// ---------------- per-node attention logits ----------------

template <int CPL>
__global__ __launch_bounds__(256) void alpha_kernel(const float* __restrict__ h,
                                                    const float* __restrict__ a_src,
                                                    const float* __restrict__ a_dst,
                                                    float* __restrict__ asrc,
                                                    float* __restrict__ adst, int n) {
    const int TOTC = 64 * CPL;
    const int CH = TOTC / 4;
    int lane = threadIdx.x & 63;
    int node = blockIdx.x * 4 + (threadIdx.x >> 6);
    if (node >= n) return;
    int head = lane >> 4;
    int c0 = lane * CPL;
    int cih0 = c0 - head * CH;
    float ss = 0.f, sd = 0.f;
    const float* hp = h + (size_t)node * TOTC + c0;
    #pragma unroll
    for (int q = 0; q < CPL; ++q) {
        float v = hp[q];
        ss += v * a_src[head * CH + cih0 + q];
        sd += v * a_dst[head * CH + cih0 + q];
    }
    #pragma unroll
    for (int o = 1; o < 16; o <<= 1) {
        ss += __shfl_xor(ss, o);
        sd += __shfl_xor(sd, o);
    }
    if ((lane & 15) == 0) {
        asrc[node * 4 + head] = ss;
        adst[node * 4 + head] = sd;
    }
}

// ---------------- segment softmax + weighted aggregation ----------------
// One wave per dst node. Softmax WITHOUT max subtraction (shift-invariant;
// logits bounded ~|13| so exp is safe in fp32 — matches reference to fp
// rounding). Per 64-edge batch: phase A stages {p0..p3, s,s,s,s} (32B/edge)
// in wave-private LDS; phase B gathers h rows with float4 loads:
//   CPL==2: 32 lanes cover the 512B row, two edges per iteration.
//   CPL==4: 64 lanes cover the 1KB row, one edge per iteration.
// Denominator accumulated for free as pw += w inside phase B.

template <int CPL, bool MEAN>
__global__ __launch_bounds__(256) void aggregate_kernel(
    const float* __restrict__ h, const float* __restrict__ asrc,
    const float* __restrict__ adst, const int* __restrict__ csr_src,
    const int* __restrict__ row_ptr, const float* __restrict__ bias,
    float* __restrict__ out, int n) {
    const int ROWF = 64 * CPL;  // floats per h row
    __shared__ float lds[4][512];  // per-wave 2KB: 64 edges x 8 dwords
    int wid = threadIdx.x >> 6;
    int lane = threadIdx.x & 63;
    int node = blockIdx.x * 4 + wid;
    if (node >= n) return;
    float* Wf = lds[wid];
    int* Wi = (int*)Wf;
    int start = row_ptr[node];
    int end = row_ptr[node + 1];
    float4 ad = *(const float4*)&adst[(size_t)node * 4];

    int l32, head, j_off;
    if constexpr (CPL == 2) {
        l32 = lane & 31; head = l32 >> 3; j_off = lane >> 5;
    } else {
        l32 = lane; head = lane >> 4; j_off = 0;
    }

    float acc0 = 0.f, acc1 = 0.f, acc2 = 0.f, acc3 = 0.f, pw = 0.f;

    for (int base = start; base < end; base += 64) {
        int cnt = end - base;
        if (cnt > 64) cnt = 64;
        // ---- phase A: stage p (4 heads) and src index ----
        if (lane < cnt) {
            int s = csr_src[base + lane];
            float4 a = *(const float4*)&asrc[(size_t)s * 4];
            float e0 = a.x + ad.x; e0 = (e0 > 0.f) ? e0 : 0.2f * e0;
            float e1 = a.y + ad.y; e1 = (e1 > 0.f) ? e1 : 0.2f * e1;
            float e2 = a.z + ad.z; e2 = (e2 > 0.f) ? e2 : 0.2f * e2;
            float e3 = a.w + ad.w; e3 = (e3 > 0.f) ? e3 : 0.2f * e3;
            float4 pv = {__expf(e0), __expf(e1), __expf(e2), __expf(e3)};
            *(float4*)&Wf[lane * 8] = pv;
            int4 sv = {s, s, s, s};
            *(int4*)&Wi[lane * 8 + 4] = sv;
        }
        if constexpr (CPL == 2) {
            // pad one slot when cnt is odd so the paired loop reads defined data
            if ((cnt & 1) && lane == cnt) {
                float4 z = {0.f, 0.f, 0.f, 0.f};
                *(float4*)&Wf[lane * 8] = z;
                int4 zi = {0, 0, 0, 0};
                *(int4*)&Wi[lane * 8 + 4] = zi;
            }
        }
        __builtin_amdgcn_wave_barrier();
        asm volatile("" ::: "memory");
        // ---- phase B: gather + weighted accumulate ----
        if constexpr (CPL == 2) {
            for (int jj = 0; jj < cnt; jj += 2) {
                int j = jj + j_off;
                float w = Wf[j * 8 + head];
                int s = Wi[j * 8 + 4 + head];
                const float* hr = h + (size_t)s * 128 + l32 * 4;
                float4 v = *(const float4*)hr;
                acc0 += w * v.x;
                acc1 += w * v.y;
                acc2 += w * v.z;
                acc3 += w * v.w;
                pw += w;
            }
        } else {
            for (int j = 0; j < cnt; ++j) {
                float w = Wf[j * 8 + head];
                int s = Wi[j * 8 + 4 + head];
                const float* hr = h + (size_t)s * 256 + lane * 4;
                float4 v = *(const float4*)hr;
                acc0 += w * v.x;
                acc1 += w * v.y;
                acc2 += w * v.z;
                acc3 += w * v.w;
                pw += w;
            }
        }
        __builtin_amdgcn_wave_barrier();
        asm volatile("" ::: "memory");
    }

    if constexpr (!MEAN) {
        // combine the two halves (each processed half the edges)
        acc0 += __shfl_xor(acc0, 32);
        acc1 += __shfl_xor(acc1, 32);
        acc2 += __shfl_xor(acc2, 32);
        acc3 += __shfl_xor(acc3, 32);
        pw += __shfl_xor(pw, 32);
        if (lane < 32) {
            float inv = 1.f / (pw + 1e-16f);
            float4 b = *(const float4*)&bias[l32 * 4];
            float4 o;
            o.x = acc0 * inv + b.x;
            o.y = acc1 * inv + b.y;
            o.z = acc2 * inv + b.z;
            o.w = acc3 * inv + b.w;
            *(float4*)&out[(size_t)node * 128 + l32 * 4] = o;
        }
    } else {
        float inv = 1.f / (pw + 1e-16f);
        float r0 = acc0 * inv, r1 = acc1 * inv, r2 = acc2 * inv, r3 = acc3 * inv;
        r0 += __shfl_xor(r0, 16); r0 += __shfl_xor(r0, 32);
        r1 += __shfl_xor(r1, 16); r1 += __shfl_xor(r1, 32);
        r2 += __shfl_xor(r2, 16); r2 += __shfl_xor(r2, 32);
        r3 += __shfl_xor(r3, 16); r3 += __shfl_xor(r3, 32);
        if (lane < 16) {
            float4 b = *(const float4*)&bias[lane * 4];
            float4 o;
            o.x = 0.25f * r0 + b.x;
            o.y = 0.25f * r1 + b.y;
            o.z = 0.25f * r2 + b.z;
            o.w = 0.25f * r3 + b.w;
            *(float4*)&out[(size_t)node * 64 + lane * 4] = o;
        }
    }
}

// ---------------- launch ----------------

extern "C" void kernel_launch(void* const* d_in, const int* in_sizes, int n_in,
                              void* d_out, int out_size, void* d_ws, size_t ws_size,
                              hipStream_t stream) {
    const float* x = (const float*)d_in[0];
    const int* ei = (const int*)d_in[1];
    const int* src = ei;
    const int* dst = ei + NEDGES;
    const float* W1 = (const float*)d_in[2];
    const float* as1 = (const float*)d_in[3];
    const float* ad1 = (const float*)d_in[4];
    const float* b1 = (const float*)d_in[5];
    const float* W2 = (const float*)d_in[6];
    const float* as2 = (const float*)d_in[7];
    const float* ad2 = (const float*)d_in[8];
    const float* b2 = (const float*)d_in[9];
    const float* W3 = (const float*)d_in[10];
    const float* as3 = (const float*)d_in[11];
    const float* ad3 = (const float*)d_in[12];
    const float* b3 = (const float*)d_in[13];

    char* ws = (char*)d_ws;
    size_t off = 0;
    auto take = [&](size_t bytes) -> char* {
        char* p = ws + off;
        off = (off + bytes + 255) & ~(size_t)255;
        return p;
    };
    int* csr = (int*)take((size_t)NEDGES * 4);
    int* row_ptr = (int*)take((size_t)(NNODES + 1) * 4);
    int* counts = (int*)take((size_t)NNODES * 4);
    int* cursor = (int*)take((size_t)NNODES * 4);
    int* bsums = (int*)take(1024 * 4);
    float* asrc = (float*)take((size_t)NNODES * 4 * 4);
    float* adst = (float*)take((size_t)NNODES * 4 * 4);
    float* hbuf = (float*)take((size_t)NNODES * 256 * 4);
    float* buf1 = (float*)take((size_t)NNODES * 128 * 4);
    float* outp = (float*)d_out;

    int nbN = (NNODES + 255) / 256;
    int nbE = (NEDGES + 255) / 256;
    int gnode4 = (NNODES + 3) / 4;

    zero_i32<<<nbN, 256, 0, stream>>>(counts, NNODES);
    hist_kernel<<<nbE, 256, 0, stream>>>(dst, counts, NEDGES);
    scan1_kernel<<<nbN, 256, 0, stream>>>(counts, row_ptr, bsums, NNODES);
    scan2_kernel<<<1, 256, 0, stream>>>(bsums, nbN);
    scan3_kernel<<<nbN, 256, 0, stream>>>(row_ptr, bsums, NNODES);
    zero_i32<<<nbN, 256, 0, stream>>>(cursor, NNODES);
    fill_kernel<<<nbE, 256, 0, stream>>>(src, dst, row_ptr, cursor, csr, NEDGES);

    dim3 g128((NNODES + 63) / 64, 1);
    dim3 g256((NNODES + 63) / 64, 2);

    gemm_kernel<<<g128, 256, 0, stream>>>(x, W1, hbuf, NNODES, 128);
    alpha_kernel<2><<<gnode4, 256, 0, stream>>>(hbuf, as1, ad1, asrc, adst, NNODES);
    aggregate_kernel<2, false><<<gnode4, 256, 0, stream>>>(hbuf, asrc, adst, csr, row_ptr, b1, buf1, NNODES);

    gemm_kernel<<<g128, 256, 0, stream>>>(buf1, W2, hbuf, NNODES, 128);
    alpha_kernel<2><<<gnode4, 256, 0, stream>>>(hbuf, as2, ad2, asrc, adst, NNODES);
    aggregate_kernel<2, false><<<gnode4, 256, 0, stream>>>(hbuf, asrc, adst, csr, row_ptr, b2, buf1, NNODES);

    gemm_kernel<<<g256, 256, 0, stream>>>(buf1, W3, hbuf, NNODES, 256);
    alpha_kernel<4><<<gnode4, 256, 0, stream>>>(hbuf, as3, ad3, asrc, adst, NNODES);
    aggregate_kernel<4, true><<<gnode4, 256, 0, stream>>>(hbuf, asrc, adst, csr, row_ptr, b3, outp, NNODES);
}

// Round 3
// 493.212 us; speedup vs baseline: 1.1198x; 1.0444x over previous
//
#include <hip/hip_runtime.h>
#include <math.h>

#define NNODES 50000
#define NEDGES 800000

// ---------------- CSR construction ----------------

__global__ void zero_i32(int* __restrict__ p, int n) {
    int i = blockIdx.x * 256 + threadIdx.x;
    if (i < n) p[i] = 0;
}

__global__ void hist_kernel(const int* __restrict__ dst, int* __restrict__ counts, int e) {
    int i = blockIdx.x * 256 + threadIdx.x;
    if (i < e) atomicAdd(&counts[dst[i]], 1);
}

__global__ void scan1_kernel(const int* __restrict__ counts, int* __restrict__ row_ptr,
                             int* __restrict__ bsums, int n) {
    __shared__ int s[256];
    int tid = threadIdx.x;
    int i = blockIdx.x * 256 + tid;
    int v = (i < n) ? counts[i] : 0;
    s[tid] = v;
    __syncthreads();
    #pragma unroll
    for (int o = 1; o < 256; o <<= 1) {
        int t = (tid >= o) ? s[tid - o] : 0;
        __syncthreads();
        s[tid] += t;
        __syncthreads();
    }
    if (i < n) row_ptr[i + 1] = s[tid];
    if (tid == 255) bsums[blockIdx.x] = s[255];
}

__global__ void scan2_kernel(int* __restrict__ bsums, int nb) {
    __shared__ int s[256];
    int tid = threadIdx.x;
    int v = (tid < nb) ? bsums[tid] : 0;
    s[tid] = v;
    __syncthreads();
    #pragma unroll
    for (int o = 1; o < 256; o <<= 1) {
        int t = (tid >= o) ? s[tid - o] : 0;
        __syncthreads();
        s[tid] += t;
        __syncthreads();
    }
    if (tid < nb) bsums[tid] = s[tid] - v;  // exclusive
}

__global__ void scan3_kernel(int* __restrict__ row_ptr, const int* __restrict__ bsums, int n) {
    int i = blockIdx.x * 256 + threadIdx.x;
    if (i < n) row_ptr[i + 1] += bsums[blockIdx.x];
    if (i == 0) row_ptr[0] = 0;
}

__global__ void fill_kernel(const int* __restrict__ src, const int* __restrict__ dst,
                            const int* __restrict__ row_ptr, int* __restrict__ cursor,
                            int* __restrict__ csr_src, int e) {
    int i = blockIdx.x * 256 + threadIdx.x;
    if (i < e) {
        int d = dst[i];
        int pos = atomicAdd(&cursor[d], 1);
        csr_src[row_ptr[d] + pos] = src[i];
    }
}

// ---------------- GEMM + fused per-node attention logits ----------------
// H[n][M] = A[n][128] @ W[128][M]; epilogue computes
// asrc[n][4], adst[n][4] (per-head dot of the H row with a_src/a_dst).
// Requires col-tile (128) to contain whole heads: CH in {32, 64}.

template <int CH>
__global__ __launch_bounds__(256) void gemm_fused(const float* __restrict__ A,
                                                  const float* __restrict__ W,
                                                  const float* __restrict__ a_src,
                                                  const float* __restrict__ a_dst,
                                                  float* __restrict__ H,
                                                  float* __restrict__ asrc,
                                                  float* __restrict__ adst, int n, int M) {
    __shared__ float As[32][65];
    __shared__ float Bs[32][128];
    int tid = threadIdx.x;
    int tr = tid >> 4;
    int tc = tid & 15;
    int row0 = blockIdx.x * 64;
    int col0 = blockIdx.y * 128;
    float acc[4][8];
    #pragma unroll
    for (int r = 0; r < 4; ++r)
        #pragma unroll
        for (int j = 0; j < 8; ++j) acc[r][j] = 0.f;

    for (int k0 = 0; k0 < 128; k0 += 32) {
        #pragma unroll
        for (int i = 0; i < 8; ++i) {
            int flat = tid + i * 256;
            int r = flat >> 5, kk = flat & 31;
            int gr = row0 + r;
            As[kk][r] = (gr < n) ? A[(size_t)gr * 128 + k0 + kk] : 0.f;
        }
        #pragma unroll
        for (int i = 0; i < 16; ++i) {
            int flat = tid + i * 256;
            int kk = flat >> 7, j = flat & 127;
            Bs[kk][j] = W[(size_t)(k0 + kk) * M + col0 + j];
        }
        __syncthreads();
        #pragma unroll
        for (int kk = 0; kk < 32; ++kk) {
            float a0 = As[kk][tr * 4 + 0];
            float a1 = As[kk][tr * 4 + 1];
            float a2 = As[kk][tr * 4 + 2];
            float a3 = As[kk][tr * 4 + 3];
            float4 b0 = *(const float4*)&Bs[kk][tc * 8];
            float4 b1 = *(const float4*)&Bs[kk][tc * 8 + 4];
            float bb[8] = {b0.x, b0.y, b0.z, b0.w, b1.x, b1.y, b1.z, b1.w};
            #pragma unroll
            for (int j = 0; j < 8; ++j) {
                acc[0][j] += a0 * bb[j];
                acc[1][j] += a1 * bb[j];
                acc[2][j] += a2 * bb[j];
                acc[3][j] += a3 * bb[j];
            }
        }
        __syncthreads();
    }

    // store H tile
    #pragma unroll
    for (int r = 0; r < 4; ++r) {
        int gr = row0 + tr * 4 + r;
        if (gr < n) {
            float4 o0 = {acc[r][0], acc[r][1], acc[r][2], acc[r][3]};
            float4 o1 = {acc[r][4], acc[r][5], acc[r][6], acc[r][7]};
            *(float4*)&H[(size_t)gr * M + col0 + tc * 8] = o0;
            *(float4*)&H[(size_t)gr * M + col0 + tc * 8 + 4] = o1;
        }
    }

    // fused alpha epilogue
    int head = (col0 + tc * 8) / CH;     // global head index
    int cih = (tc * 8) % CH;             // channel-in-head of this thread's 8 cols
    float4 s0 = *(const float4*)&a_src[head * CH + cih];
    float4 s1 = *(const float4*)&a_src[head * CH + cih + 4];
    float4 d0 = *(const float4*)&a_dst[head * CH + cih];
    float4 d1 = *(const float4*)&a_dst[head * CH + cih + 4];
    const int G = CH / 8;  // threads per head group (4 or 8)
    #pragma unroll
    for (int r = 0; r < 4; ++r) {
        float ss = acc[r][0] * s0.x + acc[r][1] * s0.y + acc[r][2] * s0.z + acc[r][3] * s0.w
                 + acc[r][4] * s1.x + acc[r][5] * s1.y + acc[r][6] * s1.z + acc[r][7] * s1.w;
        float sd = acc[r][0] * d0.x + acc[r][1] * d0.y + acc[r][2] * d0.z + acc[r][3] * d0.w
                 + acc[r][4] * d1.x + acc[r][5] * d1.y + acc[r][6] * d1.z + acc[r][7] * d1.w;
        #pragma unroll
        for (int o = 1; o < G; o <<= 1) {
            ss += __shfl_xor(ss, o);
            sd += __shfl_xor(sd, o);
        }
        int gr = row0 + tr * 4 + r;
        if ((tc & (G - 1)) == 0 && gr < n) {
            asrc[(size_t)gr * 4 + head] = ss;
            adst[(size_t)gr * 4 + head] = sd;
        }
    }
}

// ---------------- segment softmax + weighted aggregation ----------------
// One wave per dst node; softmax without max subtraction (shift-invariant,
// logits bounded, fp32-safe). Phase A stages p (per head, SoA pad-66:
// conflict-free) and src in wave-private LDS; phase B (unrolled x4 for
// memory-level parallelism) gathers h rows with float4 loads:
//   CPL==2: 32 lanes cover the 512B row, 2 edges per j-step.
//   CPL==4: 64 lanes cover the 1KB row, 1 edge per j-step.

template <int CPL, bool MEAN>
__global__ __launch_bounds__(256) void aggregate_kernel(
    const float* __restrict__ h, const float* __restrict__ asrc,
    const float* __restrict__ adst, const int* __restrict__ csr_src,
    const int* __restrict__ row_ptr, const float* __restrict__ bias,
    float* __restrict__ out, int n) {
    __shared__ float lds[4][332];  // per wave: Wp[4][66] + Ws[64]
    int wid = threadIdx.x >> 6;
    int lane = threadIdx.x & 63;
    int node = blockIdx.x * 4 + wid;
    if (node >= n) return;
    float* Wp = lds[wid];
    int* Ws = (int*)&lds[wid][264];
    int start = row_ptr[node];
    int end = row_ptr[node + 1];
    float4 ad = *(const float4*)&adst[(size_t)node * 4];

    int l32, head, j_off;
    if constexpr (CPL == 2) {
        l32 = lane & 31; head = l32 >> 3; j_off = lane >> 5;
    } else {
        l32 = lane; head = lane >> 4; j_off = 0;
    }
    int hoff = head * 66;

    float acc0 = 0.f, acc1 = 0.f, acc2 = 0.f, acc3 = 0.f, pw = 0.f;

    for (int base = start; base < end; base += 64) {
        int cnt = end - base;
        if (cnt > 64) cnt = 64;
        // ---- phase A: stage p (4 heads, SoA) and src index ----
        int s = 0;
        float4 pv = {0.f, 0.f, 0.f, 0.f};
        if (lane < cnt) {
            s = csr_src[base + lane];
            float4 a = *(const float4*)&asrc[(size_t)s * 4];
            float e0 = a.x + ad.x; e0 = (e0 > 0.f) ? e0 : 0.2f * e0;
            float e1 = a.y + ad.y; e1 = (e1 > 0.f) ? e1 : 0.2f * e1;
            float e2 = a.z + ad.z; e2 = (e2 > 0.f) ? e2 : 0.2f * e2;
            float e3 = a.w + ad.w; e3 = (e3 > 0.f) ? e3 : 0.2f * e3;
            pv.x = __expf(e0); pv.y = __expf(e1); pv.z = __expf(e2); pv.w = __expf(e3);
        }
        Wp[0 * 66 + lane] = pv.x;
        Wp[1 * 66 + lane] = pv.y;
        Wp[2 * 66 + lane] = pv.z;
        Wp[3 * 66 + lane] = pv.w;
        Ws[lane] = s;
        __builtin_amdgcn_wave_barrier();
        asm volatile("" ::: "memory");
        // ---- phase B: gather + weighted accumulate ----
        if constexpr (CPL == 2) {
            #pragma unroll 4
            for (int jj = 0; jj < cnt; jj += 2) {
                int j = jj + j_off;
                float w = Wp[hoff + j];
                int s2 = Ws[j];
                float4 v = *(const float4*)(h + (size_t)s2 * 128 + l32 * 4);
                acc0 += w * v.x;
                acc1 += w * v.y;
                acc2 += w * v.z;
                acc3 += w * v.w;
                pw += w;
            }
        } else {
            #pragma unroll 4
            for (int j = 0; j < cnt; ++j) {
                float w = Wp[hoff + j];
                int s2 = Ws[j];
                float4 v = *(const float4*)(h + (size_t)s2 * 256 + lane * 4);
                acc0 += w * v.x;
                acc1 += w * v.y;
                acc2 += w * v.z;
                acc3 += w * v.w;
                pw += w;
            }
        }
        __builtin_amdgcn_wave_barrier();
        asm volatile("" ::: "memory");
    }

    if constexpr (!MEAN) {
        acc0 += __shfl_xor(acc0, 32);
        acc1 += __shfl_xor(acc1, 32);
        acc2 += __shfl_xor(acc2, 32);
        acc3 += __shfl_xor(acc3, 32);
        pw += __shfl_xor(pw, 32);
        if (lane < 32) {
            float inv = 1.f / (pw + 1e-16f);
            float4 b = *(const float4*)&bias[l32 * 4];
            float4 o;
            o.x = acc0 * inv + b.x;
            o.y = acc1 * inv + b.y;
            o.z = acc2 * inv + b.z;
            o.w = acc3 * inv + b.w;
            *(float4*)&out[(size_t)node * 128 + l32 * 4] = o;
        }
    } else {
        float inv = 1.f / (pw + 1e-16f);
        float r0 = acc0 * inv, r1 = acc1 * inv, r2 = acc2 * inv, r3 = acc3 * inv;
        r0 += __shfl_xor(r0, 16); r0 += __shfl_xor(r0, 32);
        r1 += __shfl_xor(r1, 16); r1 += __shfl_xor(r1, 32);
        r2 += __shfl_xor(r2, 16); r2 += __shfl_xor(r2, 32);
        r3 += __shfl_xor(r3, 16); r3 += __shfl_xor(r3, 32);
        if (lane < 16) {
            float4 b = *(const float4*)&bias[lane * 4];
            float4 o;
            o.x = 0.25f * r0 + b.x;
            o.y = 0.25f * r1 + b.y;
            o.z = 0.25f * r2 + b.z;
            o.w = 0.25f * r3 + b.w;
            *(float4*)&out[(size_t)node * 64 + lane * 4] = o;
        }
    }
}

// ---------------- launch ----------------

extern "C" void kernel_launch(void* const* d_in, const int* in_sizes, int n_in,
                              void* d_out, int out_size, void* d_ws, size_t ws_size,
                              hipStream_t stream) {
    const float* x = (const float*)d_in[0];
    const int* ei = (const int*)d_in[1];
    const int* src = ei;
    const int* dst = ei + NEDGES;
    const float* W1 = (const float*)d_in[2];
    const float* as1 = (const float*)d_in[3];
    const float* ad1 = (const float*)d_in[4];
    const float* b1 = (const float*)d_in[5];
    const float* W2 = (const float*)d_in[6];
    const float* as2 = (const float*)d_in[7];
    const float* ad2 = (const float*)d_in[8];
    const float* b2 = (const float*)d_in[9];
    const float* W3 = (const float*)d_in[10];
    const float* as3 = (const float*)d_in[11];
    const float* ad3 = (const float*)d_in[12];
    const float* b3 = (const float*)d_in[13];

    char* ws = (char*)d_ws;
    size_t off = 0;
    auto take = [&](size_t bytes) -> char* {
        char* p = ws + off;
        off = (off + bytes + 255) & ~(size_t)255;
        return p;
    };
    int* csr = (int*)take((size_t)NEDGES * 4);
    int* row_ptr = (int*)take((size_t)(NNODES + 1) * 4);
    int* counts = (int*)take((size_t)NNODES * 4);
    int* cursor = (int*)take((size_t)NNODES * 4);
    int* bsums = (int*)take(1024 * 4);
    float* asrc = (float*)take((size_t)NNODES * 4 * 4);
    float* adst = (float*)take((size_t)NNODES * 4 * 4);
    float* hbuf = (float*)take((size_t)NNODES * 256 * 4);
    float* buf1 = (float*)take((size_t)NNODES * 128 * 4);
    float* outp = (float*)d_out;

    int nbN = (NNODES + 255) / 256;
    int nbE = (NEDGES + 255) / 256;
    int gnode4 = (NNODES + 3) / 4;

    zero_i32<<<nbN, 256, 0, stream>>>(counts, NNODES);
    hist_kernel<<<nbE, 256, 0, stream>>>(dst, counts, NEDGES);
    scan1_kernel<<<nbN, 256, 0, stream>>>(counts, row_ptr, bsums, NNODES);
    scan2_kernel<<<1, 256, 0, stream>>>(bsums, nbN);
    scan3_kernel<<<nbN, 256, 0, stream>>>(row_ptr, bsums, NNODES);
    zero_i32<<<nbN, 256, 0, stream>>>(cursor, NNODES);
    fill_kernel<<<nbE, 256, 0, stream>>>(src, dst, row_ptr, cursor, csr, NEDGES);

    dim3 g128((NNODES + 63) / 64, 1);
    dim3 g256((NNODES + 63) / 64, 2);

    gemm_fused<32><<<g128, 256, 0, stream>>>(x, W1, as1, ad1, hbuf, asrc, adst, NNODES, 128);
    aggregate_kernel<2, false><<<gnode4, 256, 0, stream>>>(hbuf, asrc, adst, csr, row_ptr, b1, buf1, NNODES);

    gemm_fused<32><<<g128, 256, 0, stream>>>(buf1, W2, as2, ad2, hbuf, asrc, adst, NNODES, 128);
    aggregate_kernel<2, false><<<gnode4, 256, 0, stream>>>(hbuf, asrc, adst, csr, row_ptr, b2, buf1, NNODES);

    gemm_fused<64><<<g256, 256, 0, stream>>>(buf1, W3, as3, ad3, hbuf, asrc, adst, NNODES, 256);
    aggregate_kernel<4, true><<<gnode4, 256, 0, stream>>>(hbuf, asrc, adst, csr, row_ptr, b3, outp, NNODES);
}

// Round 4
// 383.848 us; speedup vs baseline: 1.4389x; 1.2849x over previous
//
#include <hip/hip_runtime.h>
#include <hip/hip_fp16.h>
#include <math.h>

#define NNODES 50000
#define NEDGES 800000

// ---------------- CSR construction ----------------

__global__ void zero_i32(int* __restrict__ p, int n) {
    int i = blockIdx.x * 256 + threadIdx.x;
    if (i < n) p[i] = 0;
}

__global__ void hist_kernel(const int* __restrict__ dst, int* __restrict__ counts, int e) {
    int i = blockIdx.x * 256 + threadIdx.x;
    if (i < e) atomicAdd(&counts[dst[i]], 1);
}

__global__ void scan1_kernel(const int* __restrict__ counts, int* __restrict__ row_ptr,
                             int* __restrict__ bsums, int n) {
    __shared__ int s[256];
    int tid = threadIdx.x;
    int i = blockIdx.x * 256 + tid;
    int v = (i < n) ? counts[i] : 0;
    s[tid] = v;
    __syncthreads();
    #pragma unroll
    for (int o = 1; o < 256; o <<= 1) {
        int t = (tid >= o) ? s[tid - o] : 0;
        __syncthreads();
        s[tid] += t;
        __syncthreads();
    }
    if (i < n) row_ptr[i + 1] = s[tid];
    if (tid == 255) bsums[blockIdx.x] = s[255];
}

__global__ void scan2_kernel(int* __restrict__ bsums, int nb) {
    __shared__ int s[256];
    int tid = threadIdx.x;
    int v = (tid < nb) ? bsums[tid] : 0;
    s[tid] = v;
    __syncthreads();
    #pragma unroll
    for (int o = 1; o < 256; o <<= 1) {
        int t = (tid >= o) ? s[tid - o] : 0;
        __syncthreads();
        s[tid] += t;
        __syncthreads();
    }
    if (tid < nb) bsums[tid] = s[tid] - v;  // exclusive
}

__global__ void scan3_kernel(int* __restrict__ row_ptr, const int* __restrict__ bsums, int n) {
    int i = blockIdx.x * 256 + threadIdx.x;
    if (i < n) row_ptr[i + 1] += bsums[blockIdx.x];
    if (i == 0) row_ptr[0] = 0;
}

__global__ void fill_kernel(const int* __restrict__ src, const int* __restrict__ dst,
                            const int* __restrict__ row_ptr, int* __restrict__ cursor,
                            int* __restrict__ csr_src, int e) {
    int i = blockIdx.x * 256 + threadIdx.x;
    if (i < e) {
        int d = dst[i];
        int pos = atomicAdd(&cursor[d], 1);
        csr_src[row_ptr[d] + pos] = src[i];
    }
}

// ---------------- GEMM + fused per-node attention logits ----------------
// H[n][M] (fp16) = A[n][128] @ W[128][M]; epilogue computes asrc[n][4],
// adst[n][4] from the fp32 accumulators (no precision loss on logits).
// Requires col-tile (128) to contain whole heads: CH in {32, 64}.

template <int CH>
__global__ __launch_bounds__(256) void gemm_fused(const float* __restrict__ A,
                                                  const float* __restrict__ W,
                                                  const float* __restrict__ a_src,
                                                  const float* __restrict__ a_dst,
                                                  __half* __restrict__ H,
                                                  float* __restrict__ asrc,
                                                  float* __restrict__ adst, int n, int M) {
    __shared__ float As[32][65];
    __shared__ float Bs[32][128];
    int tid = threadIdx.x;
    int tr = tid >> 4;
    int tc = tid & 15;
    int row0 = blockIdx.x * 64;
    int col0 = blockIdx.y * 128;
    float acc[4][8];
    #pragma unroll
    for (int r = 0; r < 4; ++r)
        #pragma unroll
        for (int j = 0; j < 8; ++j) acc[r][j] = 0.f;

    for (int k0 = 0; k0 < 128; k0 += 32) {
        #pragma unroll
        for (int i = 0; i < 8; ++i) {
            int flat = tid + i * 256;
            int r = flat >> 5, kk = flat & 31;
            int gr = row0 + r;
            As[kk][r] = (gr < n) ? A[(size_t)gr * 128 + k0 + kk] : 0.f;
        }
        #pragma unroll
        for (int i = 0; i < 16; ++i) {
            int flat = tid + i * 256;
            int kk = flat >> 7, j = flat & 127;
            Bs[kk][j] = W[(size_t)(k0 + kk) * M + col0 + j];
        }
        __syncthreads();
        #pragma unroll
        for (int kk = 0; kk < 32; ++kk) {
            float a0 = As[kk][tr * 4 + 0];
            float a1 = As[kk][tr * 4 + 1];
            float a2 = As[kk][tr * 4 + 2];
            float a3 = As[kk][tr * 4 + 3];
            float4 b0 = *(const float4*)&Bs[kk][tc * 8];
            float4 b1 = *(const float4*)&Bs[kk][tc * 8 + 4];
            float bb[8] = {b0.x, b0.y, b0.z, b0.w, b1.x, b1.y, b1.z, b1.w};
            #pragma unroll
            for (int j = 0; j < 8; ++j) {
                acc[0][j] += a0 * bb[j];
                acc[1][j] += a1 * bb[j];
                acc[2][j] += a2 * bb[j];
                acc[3][j] += a3 * bb[j];
            }
        }
        __syncthreads();
    }

    // store H tile as fp16 (8 halves = 16B per thread, coalesced)
    #pragma unroll
    for (int r = 0; r < 4; ++r) {
        int gr = row0 + tr * 4 + r;
        if (gr < n) {
            __half2 hv[4];
            #pragma unroll
            for (int j = 0; j < 4; ++j)
                hv[j] = __floats2half2_rn(acc[r][2 * j], acc[r][2 * j + 1]);
            *(float4*)&H[(size_t)gr * M + col0 + tc * 8] = *(float4*)hv;
        }
    }

    // fused alpha epilogue (fp32)
    int head = (col0 + tc * 8) / CH;
    int cih = (tc * 8) % CH;
    float4 s0 = *(const float4*)&a_src[head * CH + cih];
    float4 s1 = *(const float4*)&a_src[head * CH + cih + 4];
    float4 d0 = *(const float4*)&a_dst[head * CH + cih];
    float4 d1 = *(const float4*)&a_dst[head * CH + cih + 4];
    const int G = CH / 8;
    #pragma unroll
    for (int r = 0; r < 4; ++r) {
        float ss = acc[r][0] * s0.x + acc[r][1] * s0.y + acc[r][2] * s0.z + acc[r][3] * s0.w
                 + acc[r][4] * s1.x + acc[r][5] * s1.y + acc[r][6] * s1.z + acc[r][7] * s1.w;
        float sd = acc[r][0] * d0.x + acc[r][1] * d0.y + acc[r][2] * d0.z + acc[r][3] * d0.w
                 + acc[r][4] * d1.x + acc[r][5] * d1.y + acc[r][6] * d1.z + acc[r][7] * d1.w;
        #pragma unroll
        for (int o = 1; o < G; o <<= 1) {
            ss += __shfl_xor(ss, o);
            sd += __shfl_xor(sd, o);
        }
        int gr = row0 + tr * 4 + r;
        if ((tc & (G - 1)) == 0 && gr < n) {
            asrc[(size_t)gr * 4 + head] = ss;
            adst[(size_t)gr * 4 + head] = sd;
        }
    }
}

// ---------------- segment softmax + weighted aggregation ----------------
// One wave per dst node; softmax without max subtraction (shift-invariant,
// logits bounded, fp32-safe). Phase A stages p (per head, SoA pad-66) and
// src in wave-private LDS; phase B gathers fp16 h rows with 8B loads
// (fp32 accumulate):
//   CPL==2: 32 lanes x 4 halves cover the 256B row, 2 edges per j-step.
//   CPL==4: 64 lanes x 4 halves cover the 512B row, 1 edge per j-step.

template <int CPL, bool MEAN>
__global__ __launch_bounds__(256) void aggregate_kernel(
    const __half* __restrict__ h, const float* __restrict__ asrc,
    const float* __restrict__ adst, const int* __restrict__ csr_src,
    const int* __restrict__ row_ptr, const float* __restrict__ bias,
    float* __restrict__ out, int n) {
    __shared__ float lds[4][332];  // per wave: Wp[4][66] + Ws[64]
    int wid = threadIdx.x >> 6;
    int lane = threadIdx.x & 63;
    int node = blockIdx.x * 4 + wid;
    if (node >= n) return;
    float* Wp = lds[wid];
    int* Ws = (int*)&lds[wid][264];
    int start = row_ptr[node];
    int end = row_ptr[node + 1];
    float4 ad = *(const float4*)&adst[(size_t)node * 4];

    int l32, head, j_off;
    if constexpr (CPL == 2) {
        l32 = lane & 31; head = l32 >> 3; j_off = lane >> 5;
    } else {
        l32 = lane; head = lane >> 4; j_off = 0;
    }
    int hoff = head * 66;

    float acc0 = 0.f, acc1 = 0.f, acc2 = 0.f, acc3 = 0.f, pw = 0.f;

    for (int base = start; base < end; base += 64) {
        int cnt = end - base;
        if (cnt > 64) cnt = 64;
        // ---- phase A: stage p (4 heads, SoA) and src index ----
        int s = 0;
        float4 pv = {0.f, 0.f, 0.f, 0.f};
        if (lane < cnt) {
            s = csr_src[base + lane];
            float4 a = *(const float4*)&asrc[(size_t)s * 4];
            float e0 = a.x + ad.x; e0 = (e0 > 0.f) ? e0 : 0.2f * e0;
            float e1 = a.y + ad.y; e1 = (e1 > 0.f) ? e1 : 0.2f * e1;
            float e2 = a.z + ad.z; e2 = (e2 > 0.f) ? e2 : 0.2f * e2;
            float e3 = a.w + ad.w; e3 = (e3 > 0.f) ? e3 : 0.2f * e3;
            pv.x = __expf(e0); pv.y = __expf(e1); pv.z = __expf(e2); pv.w = __expf(e3);
        }
        Wp[0 * 66 + lane] = pv.x;
        Wp[1 * 66 + lane] = pv.y;
        Wp[2 * 66 + lane] = pv.z;
        Wp[3 * 66 + lane] = pv.w;
        Ws[lane] = s;
        __builtin_amdgcn_wave_barrier();
        asm volatile("" ::: "memory");
        // ---- phase B: gather + weighted accumulate ----
        if constexpr (CPL == 2) {
            #pragma unroll 4
            for (int jj = 0; jj < cnt; jj += 2) {
                int j = jj + j_off;
                float w = Wp[hoff + j];
                int s2 = Ws[j];
                float2 raw = *(const float2*)(h + (size_t)s2 * 128 + l32 * 4);
                __half2 p01 = ((const __half2*)&raw)[0];
                __half2 p23 = ((const __half2*)&raw)[1];
                float2 f01 = __half22float2(p01);
                float2 f23 = __half22float2(p23);
                acc0 += w * f01.x;
                acc1 += w * f01.y;
                acc2 += w * f23.x;
                acc3 += w * f23.y;
                pw += w;
            }
        } else {
            #pragma unroll 4
            for (int j = 0; j < cnt; ++j) {
                float w = Wp[hoff + j];
                int s2 = Ws[j];
                float2 raw = *(const float2*)(h + (size_t)s2 * 256 + lane * 4);
                __half2 p01 = ((const __half2*)&raw)[0];
                __half2 p23 = ((const __half2*)&raw)[1];
                float2 f01 = __half22float2(p01);
                float2 f23 = __half22float2(p23);
                acc0 += w * f01.x;
                acc1 += w * f01.y;
                acc2 += w * f23.x;
                acc3 += w * f23.y;
                pw += w;
            }
        }
        __builtin_amdgcn_wave_barrier();
        asm volatile("" ::: "memory");
    }

    if constexpr (!MEAN) {
        acc0 += __shfl_xor(acc0, 32);
        acc1 += __shfl_xor(acc1, 32);
        acc2 += __shfl_xor(acc2, 32);
        acc3 += __shfl_xor(acc3, 32);
        pw += __shfl_xor(pw, 32);
        if (lane < 32) {
            float inv = 1.f / (pw + 1e-16f);
            float4 b = *(const float4*)&bias[l32 * 4];
            float4 o;
            o.x = acc0 * inv + b.x;
            o.y = acc1 * inv + b.y;
            o.z = acc2 * inv + b.z;
            o.w = acc3 * inv + b.w;
            *(float4*)&out[(size_t)node * 128 + l32 * 4] = o;
        }
    } else {
        float inv = 1.f / (pw + 1e-16f);
        float r0 = acc0 * inv, r1 = acc1 * inv, r2 = acc2 * inv, r3 = acc3 * inv;
        r0 += __shfl_xor(r0, 16); r0 += __shfl_xor(r0, 32);
        r1 += __shfl_xor(r1, 16); r1 += __shfl_xor(r1, 32);
        r2 += __shfl_xor(r2, 16); r2 += __shfl_xor(r2, 32);
        r3 += __shfl_xor(r3, 16); r3 += __shfl_xor(r3, 32);
        if (lane < 16) {
            float4 b = *(const float4*)&bias[lane * 4];
            float4 o;
            o.x = 0.25f * r0 + b.x;
            o.y = 0.25f * r1 + b.y;
            o.z = 0.25f * r2 + b.z;
            o.w = 0.25f * r3 + b.w;
            *(float4*)&out[(size_t)node * 64 + lane * 4] = o;
        }
    }
}

// ---------------- launch ----------------

extern "C" void kernel_launch(void* const* d_in, const int* in_sizes, int n_in,
                              void* d_out, int out_size, void* d_ws, size_t ws_size,
                              hipStream_t stream) {
    const float* x = (const float*)d_in[0];
    const int* ei = (const int*)d_in[1];
    const int* src = ei;
    const int* dst = ei + NEDGES;
    const float* W1 = (const float*)d_in[2];
    const float* as1 = (const float*)d_in[3];
    const float* ad1 = (const float*)d_in[4];
    const float* b1 = (const float*)d_in[5];
    const float* W2 = (const float*)d_in[6];
    const float* as2 = (const float*)d_in[7];
    const float* ad2 = (const float*)d_in[8];
    const float* b2 = (const float*)d_in[9];
    const float* W3 = (const float*)d_in[10];
    const float* as3 = (const float*)d_in[11];
    const float* ad3 = (const float*)d_in[12];
    const float* b3 = (const float*)d_in[13];

    char* ws = (char*)d_ws;
    size_t off = 0;
    auto take = [&](size_t bytes) -> char* {
        char* p = ws + off;
        off = (off + bytes + 255) & ~(size_t)255;
        return p;
    };
    int* csr = (int*)take((size_t)NEDGES * 4);
    int* row_ptr = (int*)take((size_t)(NNODES + 1) * 4);
    int* counts = (int*)take((size_t)NNODES * 4);
    int* cursor = (int*)take((size_t)NNODES * 4);
    int* bsums = (int*)take(1024 * 4);
    float* asrc = (float*)take((size_t)NNODES * 4 * 4);
    float* adst = (float*)take((size_t)NNODES * 4 * 4);
    __half* hbuf = (__half*)take((size_t)NNODES * 256 * 2);
    float* buf1 = (float*)take((size_t)NNODES * 128 * 4);
    float* outp = (float*)d_out;

    int nbN = (NNODES + 255) / 256;
    int nbE = (NEDGES + 255) / 256;
    int gnode4 = (NNODES + 3) / 4;

    zero_i32<<<nbN, 256, 0, stream>>>(counts, NNODES);
    hist_kernel<<<nbE, 256, 0, stream>>>(dst, counts, NEDGES);
    scan1_kernel<<<nbN, 256, 0, stream>>>(counts, row_ptr, bsums, NNODES);
    scan2_kernel<<<1, 256, 0, stream>>>(bsums, nbN);
    scan3_kernel<<<nbN, 256, 0, stream>>>(row_ptr, bsums, NNODES);
    zero_i32<<<nbN, 256, 0, stream>>>(cursor, NNODES);
    fill_kernel<<<nbE, 256, 0, stream>>>(src, dst, row_ptr, cursor, csr, NEDGES);

    dim3 g128((NNODES + 63) / 64, 1);
    dim3 g256((NNODES + 63) / 64, 2);

    gemm_fused<32><<<g128, 256, 0, stream>>>(x, W1, as1, ad1, hbuf, asrc, adst, NNODES, 128);
    aggregate_kernel<2, false><<<gnode4, 256, 0, stream>>>(hbuf, asrc, adst, csr, row_ptr, b1, buf1, NNODES);

    gemm_fused<32><<<g128, 256, 0, stream>>>(buf1, W2, as2, ad2, hbuf, asrc, adst, NNODES, 128);
    aggregate_kernel<2, false><<<gnode4, 256, 0, stream>>>(hbuf, asrc, adst, csr, row_ptr, b2, buf1, NNODES);

    gemm_fused<64><<<g256, 256, 0, stream>>>(buf1, W3, as3, ad3, hbuf, asrc, adst, NNODES, 256);
    aggregate_kernel<4, true><<<gnode4, 256, 0, stream>>>(hbuf, asrc, adst, csr, row_ptr, b3, outp, NNODES);
}

// Round 5
// 356.986 us; speedup vs baseline: 1.5472x; 1.0752x over previous
//
#include <hip/hip_runtime.h>
#include <hip/hip_fp16.h>
#include <math.h>

#define NNODES 50000
#define NEDGES 800000

// ---------------- CSR construction ----------------

__global__ void zero_i32(int* __restrict__ p, int n) {
    int i = blockIdx.x * 256 + threadIdx.x;
    if (i < n) p[i] = 0;
}

__global__ void hist_kernel(const int* __restrict__ dst, int* __restrict__ counts, int e) {
    int i = blockIdx.x * 256 + threadIdx.x;
    if (i < e) atomicAdd(&counts[dst[i]], 1);
}

__global__ void scan1_kernel(const int* __restrict__ counts, int* __restrict__ row_ptr,
                             int* __restrict__ bsums, int n) {
    __shared__ int s[256];
    int tid = threadIdx.x;
    int i = blockIdx.x * 256 + tid;
    int v = (i < n) ? counts[i] : 0;
    s[tid] = v;
    __syncthreads();
    #pragma unroll
    for (int o = 1; o < 256; o <<= 1) {
        int t = (tid >= o) ? s[tid - o] : 0;
        __syncthreads();
        s[tid] += t;
        __syncthreads();
    }
    if (i < n) row_ptr[i + 1] = s[tid];
    if (tid == 255) bsums[blockIdx.x] = s[255];
}

__global__ void scan2_kernel(int* __restrict__ bsums, int nb) {
    __shared__ int s[256];
    int tid = threadIdx.x;
    int v = (tid < nb) ? bsums[tid] : 0;
    s[tid] = v;
    __syncthreads();
    #pragma unroll
    for (int o = 1; o < 256; o <<= 1) {
        int t = (tid >= o) ? s[tid - o] : 0;
        __syncthreads();
        s[tid] += t;
        __syncthreads();
    }
    if (tid < nb) bsums[tid] = s[tid] - v;  // exclusive
}

__global__ void scan3_kernel(int* __restrict__ row_ptr, const int* __restrict__ bsums, int n) {
    int i = blockIdx.x * 256 + threadIdx.x;
    if (i < n) row_ptr[i + 1] += bsums[blockIdx.x];
    if (i == 0) row_ptr[0] = 0;
}

__global__ void fill_kernel(const int* __restrict__ src, const int* __restrict__ dst,
                            const int* __restrict__ row_ptr, int* __restrict__ cursor,
                            int* __restrict__ csr_src, int e) {
    int i = blockIdx.x * 256 + threadIdx.x;
    if (i < e) {
        int d = dst[i];
        int pos = atomicAdd(&cursor[d], 1);
        csr_src[row_ptr[d] + pos] = src[i];
    }
}

// ---------------- GEMM + fused per-node attention logits ----------------
// H[n][M] (fp16) = A[n][128] @ W[128][M]; fp32 accumulate; epilogue computes
// asrc[n][4], adst[n][4] from the fp32 accumulators.
// Tile 256 rows x 128 cols, BK=16, 256 threads, 16x8 per thread.
// Column ownership: thread wc owns quads {wc*4..+3} and {64+wc*4..+3} so the
// 16 b128 LDS reads per instruction spread over all 8 bank groups (2-way=free).

template <int CH>
__global__ __launch_bounds__(256, 2) void gemm_fused(const float* __restrict__ A,
                                                     const float* __restrict__ W,
                                                     const float* __restrict__ a_src,
                                                     const float* __restrict__ a_dst,
                                                     __half* __restrict__ H,
                                                     float* __restrict__ asrc,
                                                     float* __restrict__ adst, int n, int M) {
    __shared__ float As[16][260];  // k-major, pad 4 (2-way max on writes)
    __shared__ float Bs[16][128];
    int tid = threadIdx.x;
    int wr = tid >> 4;   // 0..15
    int wc = tid & 15;   // 0..15
    int wr4 = wr * 4, wc4 = wc * 4;
    int row0 = blockIdx.x * 256;
    int col0 = blockIdx.y * 128;

    float acc[16][8];
    #pragma unroll
    for (int r = 0; r < 16; ++r)
        #pragma unroll
        for (int j = 0; j < 8; ++j) acc[r][j] = 0.f;

    for (int k0 = 0; k0 < 128; k0 += 16) {
        // stage A: 256 rows x 16 k (k-major into As)
        #pragma unroll
        for (int h = 0; h < 4; ++h) {
            int ar = (tid >> 2) + h * 64;
            int aq = (tid & 3) * 4;
            int gr = row0 + ar;
            float4 v = {0.f, 0.f, 0.f, 0.f};
            if (gr < n) v = *(const float4*)&A[(size_t)gr * 128 + k0 + aq];
            As[aq + 0][ar] = v.x;
            As[aq + 1][ar] = v.y;
            As[aq + 2][ar] = v.z;
            As[aq + 3][ar] = v.w;
        }
        // stage B: 16 k-rows x 128 cols
        #pragma unroll
        for (int h = 0; h < 2; ++h) {
            int f = tid + h * 256;
            int br = f >> 5;
            int bc = (f & 31) * 4;
            *(float4*)&Bs[br][bc] = *(const float4*)&W[(size_t)(k0 + br) * M + col0 + bc];
        }
        __syncthreads();
        #pragma unroll
        for (int kk = 0; kk < 16; ++kk) {
            float av[16];
            *(float4*)&av[0]  = *(const float4*)&As[kk][wr4];
            *(float4*)&av[4]  = *(const float4*)&As[kk][wr4 + 64];
            *(float4*)&av[8]  = *(const float4*)&As[kk][wr4 + 128];
            *(float4*)&av[12] = *(const float4*)&As[kk][wr4 + 192];
            float4 bl = *(const float4*)&Bs[kk][wc4];
            float4 bh = *(const float4*)&Bs[kk][wc4 + 64];
            #pragma unroll
            for (int r = 0; r < 16; ++r) {
                acc[r][0] += av[r] * bl.x;
                acc[r][1] += av[r] * bl.y;
                acc[r][2] += av[r] * bl.z;
                acc[r][3] += av[r] * bl.w;
                acc[r][4] += av[r] * bh.x;
                acc[r][5] += av[r] * bh.y;
                acc[r][6] += av[r] * bh.z;
                acc[r][7] += av[r] * bh.w;
            }
        }
        __syncthreads();
    }

    // epilogue: H store (fp16) + fused alpha (fp32)
    const int G2 = CH / 4;                    // threads whose quads share heads
    int hl = (col0 + wc4) / CH;               // head of low quad
    int hh = (col0 + 64 + wc4) / CH;          // head of high quad
    int cih = wc4 % CH;                       // channel-in-head (same for both)
    float4 sl = *(const float4*)&a_src[hl * CH + cih];
    float4 sh_ = *(const float4*)&a_src[hh * CH + cih];
    float4 dl = *(const float4*)&a_dst[hl * CH + cih];
    float4 dh_ = *(const float4*)&a_dst[hh * CH + cih];

    #pragma unroll
    for (int r = 0; r < 16; ++r) {
        int gr = row0 + wr4 + (r & 3) + (r >> 2) * 64;
        bool valid = gr < n;
        if (valid) {
            __half2 lo2[2] = {__floats2half2_rn(acc[r][0], acc[r][1]),
                              __floats2half2_rn(acc[r][2], acc[r][3])};
            __half2 hi2[2] = {__floats2half2_rn(acc[r][4], acc[r][5]),
                              __floats2half2_rn(acc[r][6], acc[r][7])};
            *(float2*)&H[(size_t)gr * M + col0 + wc4] = *(float2*)lo2;
            *(float2*)&H[(size_t)gr * M + col0 + 64 + wc4] = *(float2*)hi2;
        }
        float ssl = acc[r][0] * sl.x + acc[r][1] * sl.y + acc[r][2] * sl.z + acc[r][3] * sl.w;
        float ssh = acc[r][4] * sh_.x + acc[r][5] * sh_.y + acc[r][6] * sh_.z + acc[r][7] * sh_.w;
        float sdl = acc[r][0] * dl.x + acc[r][1] * dl.y + acc[r][2] * dl.z + acc[r][3] * dl.w;
        float sdh = acc[r][4] * dh_.x + acc[r][5] * dh_.y + acc[r][6] * dh_.z + acc[r][7] * dh_.w;
        #pragma unroll
        for (int o = 1; o < G2; o <<= 1) {
            ssl += __shfl_xor(ssl, o);
            ssh += __shfl_xor(ssh, o);
            sdl += __shfl_xor(sdl, o);
            sdh += __shfl_xor(sdh, o);
        }
        if ((wc & (G2 - 1)) == 0 && valid) {
            asrc[(size_t)gr * 4 + hl] = ssl;
            asrc[(size_t)gr * 4 + hh] = ssh;
            adst[(size_t)gr * 4 + hl] = sdl;
            adst[(size_t)gr * 4 + hh] = sdh;
        }
    }
}

// ---------------- segment softmax + weighted aggregation ----------------
// One wave per dst node; softmax without max subtraction (shift-invariant,
// logits bounded, fp32-safe). Phase A stages p (per head, SoA pad-66) and
// src in wave-private LDS; phase B gathers fp16 h rows with 8B loads
// (fp32 accumulate).

template <int CPL, bool MEAN>
__global__ __launch_bounds__(256) void aggregate_kernel(
    const __half* __restrict__ h, const float* __restrict__ asrc,
    const float* __restrict__ adst, const int* __restrict__ csr_src,
    const int* __restrict__ row_ptr, const float* __restrict__ bias,
    float* __restrict__ out, int n) {
    __shared__ float lds[4][332];  // per wave: Wp[4][66] + Ws[64]
    int wid = threadIdx.x >> 6;
    int lane = threadIdx.x & 63;
    int node = blockIdx.x * 4 + wid;
    if (node >= n) return;
    float* Wp = lds[wid];
    int* Ws = (int*)&lds[wid][264];
    int start = row_ptr[node];
    int end = row_ptr[node + 1];
    float4 ad = *(const float4*)&adst[(size_t)node * 4];

    int l32, head, j_off;
    if constexpr (CPL == 2) {
        l32 = lane & 31; head = l32 >> 3; j_off = lane >> 5;
    } else {
        l32 = lane; head = lane >> 4; j_off = 0;
    }
    int hoff = head * 66;

    float acc0 = 0.f, acc1 = 0.f, acc2 = 0.f, acc3 = 0.f, pw = 0.f;

    for (int base = start; base < end; base += 64) {
        int cnt = end - base;
        if (cnt > 64) cnt = 64;
        // ---- phase A: stage p (4 heads, SoA) and src index ----
        int s = 0;
        float4 pv = {0.f, 0.f, 0.f, 0.f};
        if (lane < cnt) {
            s = csr_src[base + lane];
            float4 a = *(const float4*)&asrc[(size_t)s * 4];
            float e0 = a.x + ad.x; e0 = (e0 > 0.f) ? e0 : 0.2f * e0;
            float e1 = a.y + ad.y; e1 = (e1 > 0.f) ? e1 : 0.2f * e1;
            float e2 = a.z + ad.z; e2 = (e2 > 0.f) ? e2 : 0.2f * e2;
            float e3 = a.w + ad.w; e3 = (e3 > 0.f) ? e3 : 0.2f * e3;
            pv.x = __expf(e0); pv.y = __expf(e1); pv.z = __expf(e2); pv.w = __expf(e3);
        }
        Wp[0 * 66 + lane] = pv.x;
        Wp[1 * 66 + lane] = pv.y;
        Wp[2 * 66 + lane] = pv.z;
        Wp[3 * 66 + lane] = pv.w;
        Ws[lane] = s;
        __builtin_amdgcn_wave_barrier();
        asm volatile("" ::: "memory");
        // ---- phase B: gather + weighted accumulate ----
        if constexpr (CPL == 2) {
            #pragma unroll 4
            for (int jj = 0; jj < cnt; jj += 2) {
                int j = jj + j_off;
                float w = Wp[hoff + j];
                int s2 = Ws[j];
                float2 raw = *(const float2*)(h + (size_t)s2 * 128 + l32 * 4);
                __half2 p01 = ((const __half2*)&raw)[0];
                __half2 p23 = ((const __half2*)&raw)[1];
                float2 f01 = __half22float2(p01);
                float2 f23 = __half22float2(p23);
                acc0 += w * f01.x;
                acc1 += w * f01.y;
                acc2 += w * f23.x;
                acc3 += w * f23.y;
                pw += w;
            }
        } else {
            #pragma unroll 4
            for (int j = 0; j < cnt; ++j) {
                float w = Wp[hoff + j];
                int s2 = Ws[j];
                float2 raw = *(const float2*)(h + (size_t)s2 * 256 + lane * 4);
                __half2 p01 = ((const __half2*)&raw)[0];
                __half2 p23 = ((const __half2*)&raw)[1];
                float2 f01 = __half22float2(p01);
                float2 f23 = __half22float2(p23);
                acc0 += w * f01.x;
                acc1 += w * f01.y;
                acc2 += w * f23.x;
                acc3 += w * f23.y;
                pw += w;
            }
        }
        __builtin_amdgcn_wave_barrier();
        asm volatile("" ::: "memory");
    }

    if constexpr (!MEAN) {
        acc0 += __shfl_xor(acc0, 32);
        acc1 += __shfl_xor(acc1, 32);
        acc2 += __shfl_xor(acc2, 32);
        acc3 += __shfl_xor(acc3, 32);
        pw += __shfl_xor(pw, 32);
        if (lane < 32) {
            float inv = 1.f / (pw + 1e-16f);
            float4 b = *(const float4*)&bias[l32 * 4];
            float4 o;
            o.x = acc0 * inv + b.x;
            o.y = acc1 * inv + b.y;
            o.z = acc2 * inv + b.z;
            o.w = acc3 * inv + b.w;
            *(float4*)&out[(size_t)node * 128 + l32 * 4] = o;
        }
    } else {
        float inv = 1.f / (pw + 1e-16f);
        float r0 = acc0 * inv, r1 = acc1 * inv, r2 = acc2 * inv, r3 = acc3 * inv;
        r0 += __shfl_xor(r0, 16); r0 += __shfl_xor(r0, 32);
        r1 += __shfl_xor(r1, 16); r1 += __shfl_xor(r1, 32);
        r2 += __shfl_xor(r2, 16); r2 += __shfl_xor(r2, 32);
        r3 += __shfl_xor(r3, 16); r3 += __shfl_xor(r3, 32);
        if (lane < 16) {
            float4 b = *(const float4*)&bias[lane * 4];
            float4 o;
            o.x = 0.25f * r0 + b.x;
            o.y = 0.25f * r1 + b.y;
            o.z = 0.25f * r2 + b.z;
            o.w = 0.25f * r3 + b.w;
            *(float4*)&out[(size_t)node * 64 + lane * 4] = o;
        }
    }
}

// ---------------- launch ----------------

extern "C" void kernel_launch(void* const* d_in, const int* in_sizes, int n_in,
                              void* d_out, int out_size, void* d_ws, size_t ws_size,
                              hipStream_t stream) {
    const float* x = (const float*)d_in[0];
    const int* ei = (const int*)d_in[1];
    const int* src = ei;
    const int* dst = ei + NEDGES;
    const float* W1 = (const float*)d_in[2];
    const float* as1 = (const float*)d_in[3];
    const float* ad1 = (const float*)d_in[4];
    const float* b1 = (const float*)d_in[5];
    const float* W2 = (const float*)d_in[6];
    const float* as2 = (const float*)d_in[7];
    const float* ad2 = (const float*)d_in[8];
    const float* b2 = (const float*)d_in[9];
    const float* W3 = (const float*)d_in[10];
    const float* as3 = (const float*)d_in[11];
    const float* ad3 = (const float*)d_in[12];
    const float* b3 = (const float*)d_in[13];

    char* ws = (char*)d_ws;
    size_t off = 0;
    auto take = [&](size_t bytes) -> char* {
        char* p = ws + off;
        off = (off + bytes + 255) & ~(size_t)255;
        return p;
    };
    int* csr = (int*)take((size_t)NEDGES * 4);
    int* row_ptr = (int*)take((size_t)(NNODES + 1) * 4);
    int* counts = (int*)take((size_t)NNODES * 4);
    int* cursor = (int*)take((size_t)NNODES * 4);
    int* bsums = (int*)take(1024 * 4);
    float* asrc = (float*)take((size_t)NNODES * 4 * 4);
    float* adst = (float*)take((size_t)NNODES * 4 * 4);
    __half* hbuf = (__half*)take((size_t)NNODES * 256 * 2);
    float* buf1 = (float*)take((size_t)NNODES * 128 * 4);
    float* outp = (float*)d_out;

    int nbN = (NNODES + 255) / 256;
    int nbE = (NEDGES + 255) / 256;
    int gnode4 = (NNODES + 3) / 4;

    zero_i32<<<nbN, 256, 0, stream>>>(counts, NNODES);
    hist_kernel<<<nbE, 256, 0, stream>>>(dst, counts, NEDGES);
    scan1_kernel<<<nbN, 256, 0, stream>>>(counts, row_ptr, bsums, NNODES);
    scan2_kernel<<<1, 256, 0, stream>>>(bsums, nbN);
    scan3_kernel<<<nbN, 256, 0, stream>>>(row_ptr, bsums, NNODES);
    zero_i32<<<nbN, 256, 0, stream>>>(cursor, NNODES);
    fill_kernel<<<nbE, 256, 0, stream>>>(src, dst, row_ptr, cursor, csr, NEDGES);

    dim3 g128((NNODES + 255) / 256, 1);
    dim3 g256((NNODES + 255) / 256, 2);
    int gnodeAgg = (NNODES + 3) / 4;

    gemm_fused<32><<<g128, 256, 0, stream>>>(x, W1, as1, ad1, hbuf, asrc, adst, NNODES, 128);
    aggregate_kernel<2, false><<<gnodeAgg, 256, 0, stream>>>(hbuf, asrc, adst, csr, row_ptr, b1, buf1, NNODES);

    gemm_fused<32><<<g128, 256, 0, stream>>>(buf1, W2, as2, ad2, hbuf, asrc, adst, NNODES, 128);
    aggregate_kernel<2, false><<<gnodeAgg, 256, 0, stream>>>(hbuf, asrc, adst, csr, row_ptr, b2, buf1, NNODES);

    gemm_fused<64><<<g256, 256, 0, stream>>>(buf1, W3, as3, ad3, hbuf, asrc, adst, NNODES, 256);
    aggregate_kernel<4, true><<<gnodeAgg, 256, 0, stream>>>(hbuf, asrc, adst, csr, row_ptr, b3, outp, NNODES);
}

// Round 6
// 304.149 us; speedup vs baseline: 1.8159x; 1.1737x over previous
//
#include <hip/hip_runtime.h>
#include <hip/hip_fp16.h>
#include <math.h>

#define NNODES 50000
#define NEDGES 800000

typedef _Float16 half8 __attribute__((ext_vector_type(8)));
typedef float floatx4 __attribute__((ext_vector_type(4)));

// ---------------- CSR construction ----------------

__global__ void zero_i32(int* __restrict__ p, int n) {
    int i = blockIdx.x * 256 + threadIdx.x;
    if (i < n) p[i] = 0;
}

__global__ void hist_kernel(const int* __restrict__ dst, int* __restrict__ counts, int e) {
    int i = blockIdx.x * 256 + threadIdx.x;
    if (i < e) atomicAdd(&counts[dst[i]], 1);
}

__global__ void scan1_kernel(const int* __restrict__ counts, int* __restrict__ row_ptr,
                             int* __restrict__ bsums, int n) {
    __shared__ int s[256];
    int tid = threadIdx.x;
    int i = blockIdx.x * 256 + tid;
    int v = (i < n) ? counts[i] : 0;
    s[tid] = v;
    __syncthreads();
    #pragma unroll
    for (int o = 1; o < 256; o <<= 1) {
        int t = (tid >= o) ? s[tid - o] : 0;
        __syncthreads();
        s[tid] += t;
        __syncthreads();
    }
    if (i < n) row_ptr[i + 1] = s[tid];
    if (tid == 255) bsums[blockIdx.x] = s[255];
}

__global__ void scan2_kernel(int* __restrict__ bsums, int nb) {
    __shared__ int s[256];
    int tid = threadIdx.x;
    int v = (tid < nb) ? bsums[tid] : 0;
    s[tid] = v;
    __syncthreads();
    #pragma unroll
    for (int o = 1; o < 256; o <<= 1) {
        int t = (tid >= o) ? s[tid - o] : 0;
        __syncthreads();
        s[tid] += t;
        __syncthreads();
    }
    if (tid < nb) bsums[tid] = s[tid] - v;  // exclusive
}

__global__ void scan3_kernel(int* __restrict__ row_ptr, const int* __restrict__ bsums, int n) {
    int i = blockIdx.x * 256 + threadIdx.x;
    if (i < n) row_ptr[i + 1] += bsums[blockIdx.x];
    if (i == 0) row_ptr[0] = 0;
}

__global__ void fill_kernel(const int* __restrict__ src, const int* __restrict__ dst,
                            const int* __restrict__ row_ptr, int* __restrict__ cursor,
                            int* __restrict__ csr_src, int e) {
    int i = blockIdx.x * 256 + threadIdx.x;
    if (i < e) {
        int d = dst[i];
        int pos = atomicAdd(&cursor[d], 1);
        csr_src[row_ptr[d] + pos] = src[i];
    }
}

// ---------------- dtype converts ----------------

__global__ void convert_x(const float* __restrict__ x, __half* __restrict__ xh, int total4) {
    int i = blockIdx.x * 256 + threadIdx.x;
    if (i < total4) {
        float4 v = *(const float4*)&x[i * 4];
        __half2 a = __floats2half2_rn(v.x, v.y);
        __half2 b = __floats2half2_rn(v.z, v.w);
        uint2 st = {*(unsigned int*)&a, *(unsigned int*)&b};
        *(uint2*)&xh[i * 4] = st;
    }
}

// W[k][M] fp32 -> Wt[M][128] fp16 (transposed, n-major)
__global__ void convert_wt(const float* __restrict__ W, __half* __restrict__ Wt, int M) {
    int i = blockIdx.x * 256 + threadIdx.x;
    if (i < 128 * M) {
        int k = i / M, nn = i - k * M;
        Wt[nn * 128 + k] = __float2half(W[i]);
    }
}

// ---------------- MFMA GEMM + fused attention logits ----------------
// H[n][M] (fp16) = A[n][128](fp16) @ W[128][M], fp32 accumulate via
// v_mfma_f32_16x16x32_f16. Tile 128 rows x 64 cols, whole K=128 in LDS,
// 4 waves (2 row-halves x 2 col-halves), 32 MFMA/wave, one barrier.
// Fragment layout (verified lineage: learn_hip m89/m92): A lane l holds
// A[m=l&15][k=(l>>4)*8+j] (8 contiguous k); B lane l holds B[k=(l>>4)*8+j][n=l&15]
// (8 contiguous k of column n from n-major LDS); D lane l reg r = D[(l>>4)*4+r][l&15].
// Epilogue computes asrc/adst from fp32 accumulators.

template <int CH>
__global__ __launch_bounds__(256, 3) void gemm_mfma(const __half* __restrict__ A,
                                                    const __half* __restrict__ Wt,
                                                    const float* __restrict__ a_src,
                                                    const float* __restrict__ a_dst,
                                                    __half* __restrict__ H,
                                                    float* __restrict__ asrc,
                                                    float* __restrict__ adst, int n, int M) {
    __shared__ __half As[128][136];   // pad 8 halfs: 272B rows -> 2-way banks
    __shared__ __half Ws[64][136];
    __shared__ float scr[2][128][2];  // CH==64 cross-wave alpha combine
    int tid = threadIdx.x;
    int row0 = blockIdx.x * 128;
    int col0 = blockIdx.y * 64;

    // stage A-tile: 128 rows x 128 k
    #pragma unroll
    for (int it = 0; it < 8; ++it) {
        int flat = tid + it * 256;
        int r = flat >> 4;
        int kq = (flat & 15) * 8;
        int gr = row0 + r;
        float4 v = {0.f, 0.f, 0.f, 0.f};
        if (gr < n) v = *(const float4*)&A[(size_t)gr * 128 + kq];
        *(float4*)&As[r][kq] = v;
    }
    // stage W-tile: 64 n x 128 k (from n-major Wt)
    #pragma unroll
    for (int it = 0; it < 4; ++it) {
        int flat = tid + it * 256;
        int r = flat >> 4;
        int kq = (flat & 15) * 8;
        *(float4*)&Ws[r][kq] = *(const float4*)&Wt[(size_t)(col0 + r) * 128 + kq];
    }
    __syncthreads();

    int lane = tid & 63;
    int wid = tid >> 6;
    int wm = (wid >> 1) * 64;   // wave row offset
    int wn = (wid & 1) * 32;    // wave col offset
    int l15 = lane & 15;
    int l4 = lane >> 4;

    floatx4 acc[4][2];
    #pragma unroll
    for (int mf = 0; mf < 4; ++mf)
        #pragma unroll
        for (int nf = 0; nf < 2; ++nf) {
            floatx4 z = {0.f, 0.f, 0.f, 0.f};
            acc[mf][nf] = z;
        }

    #pragma unroll
    for (int ks = 0; ks < 4; ++ks) {
        int kb = ks * 32 + l4 * 8;
        half8 b0 = *(const half8*)&Ws[wn + l15][kb];
        half8 b1 = *(const half8*)&Ws[wn + 16 + l15][kb];
        #pragma unroll
        for (int mf = 0; mf < 4; ++mf) {
            half8 a = *(const half8*)&As[wm + mf * 16 + l15][kb];
            acc[mf][0] = __builtin_amdgcn_mfma_f32_16x16x32_f16(a, b0, acc[mf][0], 0, 0, 0);
            acc[mf][1] = __builtin_amdgcn_mfma_f32_16x16x32_f16(a, b1, acc[mf][1], 0, 0, 0);
        }
    }

    // H store (fp16). Per 16-lane group a row's 16 cols = 32 contiguous bytes.
    #pragma unroll
    for (int mf = 0; mf < 4; ++mf)
        #pragma unroll
        for (int r = 0; r < 4; ++r) {
            int gr = row0 + wm + mf * 16 + l4 * 4 + r;
            if (gr < n) {
                H[(size_t)gr * M + col0 + wn + l15] = __float2half(acc[mf][0][r]);
                H[(size_t)gr * M + col0 + wn + 16 + l15] = __float2half(acc[mf][1][r]);
            }
        }

    // fused alpha epilogue (fp32 accumulators)
    int hw = (col0 + wn) / CH;         // head of this wave's 32 cols
    int cb = (col0 + wn) % CH;         // channel base within head
    float vs0 = a_src[hw * CH + cb + l15];
    float vs1 = a_src[hw * CH + cb + 16 + l15];
    float vd0 = a_dst[hw * CH + cb + l15];
    float vd1 = a_dst[hw * CH + cb + 16 + l15];

    #pragma unroll
    for (int mf = 0; mf < 4; ++mf)
        #pragma unroll
        for (int r = 0; r < 4; ++r) {
            float ss = acc[mf][0][r] * vs0 + acc[mf][1][r] * vs1;
            float sd = acc[mf][0][r] * vd0 + acc[mf][1][r] * vd1;
            #pragma unroll
            for (int o = 1; o < 16; o <<= 1) {
                ss += __shfl_xor(ss, o);
                sd += __shfl_xor(sd, o);
            }
            if (l15 == 0) {
                int ri = wm + mf * 16 + l4 * 4 + r;
                if constexpr (CH == 32) {
                    int gr = row0 + ri;
                    if (gr < n) {
                        asrc[(size_t)gr * 4 + hw] = ss;
                        adst[(size_t)gr * 4 + hw] = sd;
                    }
                } else {
                    scr[wid & 1][ri][0] = ss;
                    scr[wid & 1][ri][1] = sd;
                }
            }
        }
    if constexpr (CH == 64) {
        __syncthreads();
        if (tid < 128) {
            int gr = row0 + tid;
            if (gr < n) {
                int head = col0 / 64;
                asrc[(size_t)gr * 4 + head] = scr[0][tid][0] + scr[1][tid][0];
                adst[(size_t)gr * 4 + head] = scr[0][tid][1] + scr[1][tid][1];
            }
        }
    }
}

// ---------------- segment softmax + weighted aggregation ----------------
// One wave per dst node; softmax without max subtraction (shift-invariant,
// logits bounded, fp32-safe). Phase A stages p (SoA pad-66) + src in
// wave-private LDS; phase B gathers fp16 h rows with 8B loads, fp32 accum.
// Layers 1/2 (!MEAN) write fp16 (feeds next GEMM); layer 3 writes fp32 d_out.

template <int CPL, bool MEAN>
__global__ __launch_bounds__(256) void aggregate_kernel(
    const __half* __restrict__ h, const float* __restrict__ asrc,
    const float* __restrict__ adst, const int* __restrict__ csr_src,
    const int* __restrict__ row_ptr, const float* __restrict__ bias,
    void* __restrict__ out_, int n) {
    __shared__ float lds[4][332];
    int wid = threadIdx.x >> 6;
    int lane = threadIdx.x & 63;
    int node = blockIdx.x * 4 + wid;
    if (node >= n) return;
    float* Wp = lds[wid];
    int* Ws = (int*)&lds[wid][264];
    int start = row_ptr[node];
    int end = row_ptr[node + 1];
    float4 ad = *(const float4*)&adst[(size_t)node * 4];

    int l32, head, j_off;
    if constexpr (CPL == 2) {
        l32 = lane & 31; head = l32 >> 3; j_off = lane >> 5;
    } else {
        l32 = lane; head = lane >> 4; j_off = 0;
    }
    int hoff = head * 66;

    float acc0 = 0.f, acc1 = 0.f, acc2 = 0.f, acc3 = 0.f, pw = 0.f;

    for (int base = start; base < end; base += 64) {
        int cnt = end - base;
        if (cnt > 64) cnt = 64;
        int s = 0;
        float4 pv = {0.f, 0.f, 0.f, 0.f};
        if (lane < cnt) {
            s = csr_src[base + lane];
            float4 a = *(const float4*)&asrc[(size_t)s * 4];
            float e0 = a.x + ad.x; e0 = (e0 > 0.f) ? e0 : 0.2f * e0;
            float e1 = a.y + ad.y; e1 = (e1 > 0.f) ? e1 : 0.2f * e1;
            float e2 = a.z + ad.z; e2 = (e2 > 0.f) ? e2 : 0.2f * e2;
            float e3 = a.w + ad.w; e3 = (e3 > 0.f) ? e3 : 0.2f * e3;
            pv.x = __expf(e0); pv.y = __expf(e1); pv.z = __expf(e2); pv.w = __expf(e3);
        }
        Wp[0 * 66 + lane] = pv.x;
        Wp[1 * 66 + lane] = pv.y;
        Wp[2 * 66 + lane] = pv.z;
        Wp[3 * 66 + lane] = pv.w;
        Ws[lane] = s;
        __builtin_amdgcn_wave_barrier();
        asm volatile("" ::: "memory");
        if constexpr (CPL == 2) {
            #pragma unroll 4
            for (int jj = 0; jj < cnt; jj += 2) {
                int j = jj + j_off;
                float w = Wp[hoff + j];
                int s2 = Ws[j];
                float2 raw = *(const float2*)(h + (size_t)s2 * 128 + l32 * 4);
                __half2 p01 = ((const __half2*)&raw)[0];
                __half2 p23 = ((const __half2*)&raw)[1];
                float2 f01 = __half22float2(p01);
                float2 f23 = __half22float2(p23);
                acc0 += w * f01.x;
                acc1 += w * f01.y;
                acc2 += w * f23.x;
                acc3 += w * f23.y;
                pw += w;
            }
        } else {
            #pragma unroll 4
            for (int j = 0; j < cnt; ++j) {
                float w = Wp[hoff + j];
                int s2 = Ws[j];
                float2 raw = *(const float2*)(h + (size_t)s2 * 256 + lane * 4);
                __half2 p01 = ((const __half2*)&raw)[0];
                __half2 p23 = ((const __half2*)&raw)[1];
                float2 f01 = __half22float2(p01);
                float2 f23 = __half22float2(p23);
                acc0 += w * f01.x;
                acc1 += w * f01.y;
                acc2 += w * f23.x;
                acc3 += w * f23.y;
                pw += w;
            }
        }
        __builtin_amdgcn_wave_barrier();
        asm volatile("" ::: "memory");
    }

    if constexpr (!MEAN) {
        acc0 += __shfl_xor(acc0, 32);
        acc1 += __shfl_xor(acc1, 32);
        acc2 += __shfl_xor(acc2, 32);
        acc3 += __shfl_xor(acc3, 32);
        pw += __shfl_xor(pw, 32);
        if (lane < 32) {
            float inv = 1.f / (pw + 1e-16f);
            float4 b = *(const float4*)&bias[l32 * 4];
            __half* out = (__half*)out_;
            __half2 ha = __floats2half2_rn(acc0 * inv + b.x, acc1 * inv + b.y);
            __half2 hb = __floats2half2_rn(acc2 * inv + b.z, acc3 * inv + b.w);
            uint2 st = {*(unsigned int*)&ha, *(unsigned int*)&hb};
            *(uint2*)&out[(size_t)node * 128 + l32 * 4] = st;
        }
    } else {
        float inv = 1.f / (pw + 1e-16f);
        float r0 = acc0 * inv, r1 = acc1 * inv, r2 = acc2 * inv, r3 = acc3 * inv;
        r0 += __shfl_xor(r0, 16); r0 += __shfl_xor(r0, 32);
        r1 += __shfl_xor(r1, 16); r1 += __shfl_xor(r1, 32);
        r2 += __shfl_xor(r2, 16); r2 += __shfl_xor(r2, 32);
        r3 += __shfl_xor(r3, 16); r3 += __shfl_xor(r3, 32);
        if (lane < 16) {
            float* out = (float*)out_;
            float4 b = *(const float4*)&bias[lane * 4];
            float4 o;
            o.x = 0.25f * r0 + b.x;
            o.y = 0.25f * r1 + b.y;
            o.z = 0.25f * r2 + b.z;
            o.w = 0.25f * r3 + b.w;
            *(float4*)&out[(size_t)node * 64 + lane * 4] = o;
        }
    }
}

// ---------------- launch ----------------

extern "C" void kernel_launch(void* const* d_in, const int* in_sizes, int n_in,
                              void* d_out, int out_size, void* d_ws, size_t ws_size,
                              hipStream_t stream) {
    const float* x = (const float*)d_in[0];
    const int* ei = (const int*)d_in[1];
    const int* src = ei;
    const int* dst = ei + NEDGES;
    const float* W1 = (const float*)d_in[2];
    const float* as1 = (const float*)d_in[3];
    const float* ad1 = (const float*)d_in[4];
    const float* b1 = (const float*)d_in[5];
    const float* W2 = (const float*)d_in[6];
    const float* as2 = (const float*)d_in[7];
    const float* ad2 = (const float*)d_in[8];
    const float* b2 = (const float*)d_in[9];
    const float* W3 = (const float*)d_in[10];
    const float* as3 = (const float*)d_in[11];
    const float* ad3 = (const float*)d_in[12];
    const float* b3 = (const float*)d_in[13];

    char* ws = (char*)d_ws;
    size_t off = 0;
    auto take = [&](size_t bytes) -> char* {
        char* p = ws + off;
        off = (off + bytes + 255) & ~(size_t)255;
        return p;
    };
    int* csr = (int*)take((size_t)NEDGES * 4);
    int* row_ptr = (int*)take((size_t)(NNODES + 1) * 4);
    int* counts = (int*)take((size_t)NNODES * 4);
    int* cursor = (int*)take((size_t)NNODES * 4);
    int* bsums = (int*)take(1024 * 4);
    float* asrc = (float*)take((size_t)NNODES * 4 * 4);
    float* adst = (float*)take((size_t)NNODES * 4 * 4);
    __half* hbuf = (__half*)take((size_t)NNODES * 256 * 2);
    __half* xh = (__half*)take((size_t)NNODES * 128 * 2);
    __half* buf1h = (__half*)take((size_t)NNODES * 128 * 2);
    __half* wt = (__half*)take((size_t)256 * 128 * 2);
    float* outp = (float*)d_out;

    int nbN = (NNODES + 255) / 256;
    int nbE = (NEDGES + 255) / 256;
    int gnodeAgg = (NNODES + 3) / 4;

    // CSR build (graph shared by all layers)
    zero_i32<<<nbN, 256, 0, stream>>>(counts, NNODES);
    hist_kernel<<<nbE, 256, 0, stream>>>(dst, counts, NEDGES);
    scan1_kernel<<<nbN, 256, 0, stream>>>(counts, row_ptr, bsums, NNODES);
    scan2_kernel<<<1, 256, 0, stream>>>(bsums, nbN);
    scan3_kernel<<<nbN, 256, 0, stream>>>(row_ptr, bsums, NNODES);
    zero_i32<<<nbN, 256, 0, stream>>>(cursor, NNODES);
    fill_kernel<<<nbE, 256, 0, stream>>>(src, dst, row_ptr, cursor, csr, NEDGES);

    // fp16 views of x
    convert_x<<<(NNODES * 128 / 4 + 255) / 256, 256, 0, stream>>>(x, xh, NNODES * 128 / 4);

    dim3 gA((NNODES + 127) / 128, 2);  // M=128
    dim3 gB((NNODES + 127) / 128, 4);  // M=256

    // layer 1
    convert_wt<<<(128 * 128 + 255) / 256, 256, 0, stream>>>(W1, wt, 128);
    gemm_mfma<32><<<gA, 256, 0, stream>>>(xh, wt, as1, ad1, hbuf, asrc, adst, NNODES, 128);
    aggregate_kernel<2, false><<<gnodeAgg, 256, 0, stream>>>(hbuf, asrc, adst, csr, row_ptr, b1, buf1h, NNODES);

    // layer 2
    convert_wt<<<(128 * 128 + 255) / 256, 256, 0, stream>>>(W2, wt, 128);
    gemm_mfma<32><<<gA, 256, 0, stream>>>(buf1h, wt, as2, ad2, hbuf, asrc, adst, NNODES, 128);
    aggregate_kernel<2, false><<<gnodeAgg, 256, 0, stream>>>(hbuf, asrc, adst, csr, row_ptr, b2, buf1h, NNODES);

    // layer 3
    convert_wt<<<(128 * 256 + 255) / 256, 256, 0, stream>>>(W3, wt, 256);
    gemm_mfma<64><<<gB, 256, 0, stream>>>(buf1h, wt, as3, ad3, hbuf, asrc, adst, NNODES, 256);
    aggregate_kernel<4, true><<<gnodeAgg, 256, 0, stream>>>(hbuf, asrc, adst, csr, row_ptr, b3, outp, NNODES);
}

// Round 7
// 295.754 us; speedup vs baseline: 1.8675x; 1.0284x over previous
//
#include <hip/hip_runtime.h>
#include <hip/hip_fp16.h>
#include <math.h>

#define NNODES 50000
#define NEDGES 800000

typedef _Float16 half8 __attribute__((ext_vector_type(8)));
typedef float floatx4 __attribute__((ext_vector_type(4)));

// ---------------- CSR construction ----------------

__global__ void zero_i32(int* __restrict__ p, int n) {
    int i = blockIdx.x * 256 + threadIdx.x;
    if (i < n) p[i] = 0;
}

__global__ void hist_kernel(const int* __restrict__ dst, int* __restrict__ counts, int e) {
    int i = blockIdx.x * 256 + threadIdx.x;
    if (i < e) atomicAdd(&counts[dst[i]], 1);
}

__global__ void scan1_kernel(const int* __restrict__ counts, int* __restrict__ row_ptr,
                             int* __restrict__ bsums, int n) {
    __shared__ int s[256];
    int tid = threadIdx.x;
    int i = blockIdx.x * 256 + tid;
    int v = (i < n) ? counts[i] : 0;
    s[tid] = v;
    __syncthreads();
    #pragma unroll
    for (int o = 1; o < 256; o <<= 1) {
        int t = (tid >= o) ? s[tid - o] : 0;
        __syncthreads();
        s[tid] += t;
        __syncthreads();
    }
    if (i < n) row_ptr[i + 1] = s[tid];
    if (tid == 255) bsums[blockIdx.x] = s[255];
}

__global__ void scan2_kernel(int* __restrict__ bsums, int nb) {
    __shared__ int s[256];
    int tid = threadIdx.x;
    int v = (tid < nb) ? bsums[tid] : 0;
    s[tid] = v;
    __syncthreads();
    #pragma unroll
    for (int o = 1; o < 256; o <<= 1) {
        int t = (tid >= o) ? s[tid - o] : 0;
        __syncthreads();
        s[tid] += t;
        __syncthreads();
    }
    if (tid < nb) bsums[tid] = s[tid] - v;  // exclusive
}

// scan3 also zero-inits cursor (saves a launch)
__global__ void scan3_kernel(int* __restrict__ row_ptr, const int* __restrict__ bsums,
                             int* __restrict__ cursor, int n) {
    int i = blockIdx.x * 256 + threadIdx.x;
    if (i < n) {
        row_ptr[i + 1] += bsums[blockIdx.x];
        cursor[i] = 0;
    }
    if (i == 0) row_ptr[0] = 0;
}

__global__ void fill_kernel(const int* __restrict__ src, const int* __restrict__ dst,
                            const int* __restrict__ row_ptr, int* __restrict__ cursor,
                            int* __restrict__ csr_src, int e) {
    int i = blockIdx.x * 256 + threadIdx.x;
    if (i < e) {
        int d = dst[i];
        int pos = atomicAdd(&cursor[d], 1);
        csr_src[row_ptr[d] + pos] = src[i];
    }
}

// ---------------- MFMA GEMM + fused attention logits ----------------
// H[n][M] (fp16) = A[n][128] @ W[128][M], fp32 accumulate via
// v_mfma_f32_16x16x32_f16. Tile 128 rows x 64 cols, whole K=128 in LDS,
// 4 waves, 32 MFMA/wave. A read as fp32 (layer 1, inline convert) or fp16.
// W read fp32 k-major and transposed+converted during staging (no Wt buffer).
// CH64 cross-wave alpha scratch overlays As (barrier after MFMA).

template <int CH, bool AF32, int LAYER>
__global__ __launch_bounds__(256, 3) void gemm_mfma(const void* __restrict__ A_,
                                                    const float* __restrict__ Wf,
                                                    const float* __restrict__ a_src,
                                                    const float* __restrict__ a_dst,
                                                    __half* __restrict__ H,
                                                    float* __restrict__ asrc,
                                                    float* __restrict__ adst, int n, int M) {
    __shared__ __half As[128][136];   // pad 8 halfs: 272B rows -> 2-way banks
    __shared__ __half Ws[64][136];
    float* scrf = (float*)&As[0][0];  // CH64 overlay: [2][128][2] floats (2KB)
    int tid = threadIdx.x;
    int row0 = blockIdx.x * 128;
    int col0 = blockIdx.y * 64;

    // stage A-tile: 128 rows x 128 k
    if constexpr (AF32) {
        const float* Af = (const float*)A_;
        #pragma unroll
        for (int it = 0; it < 8; ++it) {
            int flat = tid + it * 256;
            int r = flat >> 4;
            int kq = (flat & 15) * 8;
            int gr = row0 + r;
            float4 v0 = {0.f, 0.f, 0.f, 0.f}, v1 = {0.f, 0.f, 0.f, 0.f};
            if (gr < n) {
                v0 = *(const float4*)&Af[(size_t)gr * 128 + kq];
                v1 = *(const float4*)&Af[(size_t)gr * 128 + kq + 4];
            }
            __half2 h0 = __floats2half2_rn(v0.x, v0.y);
            __half2 h1 = __floats2half2_rn(v0.z, v0.w);
            __half2 h2 = __floats2half2_rn(v1.x, v1.y);
            __half2 h3 = __floats2half2_rn(v1.z, v1.w);
            uint4 st = {*(unsigned*)&h0, *(unsigned*)&h1, *(unsigned*)&h2, *(unsigned*)&h3};
            *(uint4*)&As[r][kq] = st;
        }
    } else {
        const __half* Ah = (const __half*)A_;
        #pragma unroll
        for (int it = 0; it < 8; ++it) {
            int flat = tid + it * 256;
            int r = flat >> 4;
            int kq = (flat & 15) * 8;
            int gr = row0 + r;
            float4 v = {0.f, 0.f, 0.f, 0.f};
            if (gr < n) v = *(const float4*)&Ah[(size_t)gr * 128 + kq];
            *(float4*)&As[r][kq] = v;
        }
    }
    // stage W-tile: transpose+convert fp32 W[k][col0+nn] -> Ws[nn][k]
    #pragma unroll
    for (int it = 0; it < 8; ++it) {
        int flat = tid + it * 256;   // 0..2047
        int k = flat >> 4;           // 0..127
        int q = flat & 15;           // 0..15
        float4 v = *(const float4*)&Wf[(size_t)k * M + col0 + q * 4];
        Ws[q * 4 + 0][k] = __float2half(v.x);
        Ws[q * 4 + 1][k] = __float2half(v.y);
        Ws[q * 4 + 2][k] = __float2half(v.z);
        Ws[q * 4 + 3][k] = __float2half(v.w);
    }
    __syncthreads();

    int lane = tid & 63;
    int wid = tid >> 6;
    int wm = (wid >> 1) * 64;   // wave row offset
    int wn = (wid & 1) * 32;    // wave col offset
    int l15 = lane & 15;
    int l4 = lane >> 4;

    floatx4 acc[4][2];
    #pragma unroll
    for (int mf = 0; mf < 4; ++mf)
        #pragma unroll
        for (int nf = 0; nf < 2; ++nf) {
            floatx4 z = {0.f, 0.f, 0.f, 0.f};
            acc[mf][nf] = z;
        }

    #pragma unroll
    for (int ks = 0; ks < 4; ++ks) {
        int kb = ks * 32 + l4 * 8;
        half8 b0 = *(const half8*)&Ws[wn + l15][kb];
        half8 b1 = *(const half8*)&Ws[wn + 16 + l15][kb];
        #pragma unroll
        for (int mf = 0; mf < 4; ++mf) {
            half8 a = *(const half8*)&As[wm + mf * 16 + l15][kb];
            acc[mf][0] = __builtin_amdgcn_mfma_f32_16x16x32_f16(a, b0, acc[mf][0], 0, 0, 0);
            acc[mf][1] = __builtin_amdgcn_mfma_f32_16x16x32_f16(a, b1, acc[mf][1], 0, 0, 0);
        }
    }
    if constexpr (CH == 64) __syncthreads();  // As reads done; scr overlay safe

    // H store (fp16)
    #pragma unroll
    for (int mf = 0; mf < 4; ++mf)
        #pragma unroll
        for (int r = 0; r < 4; ++r) {
            int gr = row0 + wm + mf * 16 + l4 * 4 + r;
            if (gr < n) {
                H[(size_t)gr * M + col0 + wn + l15] = __float2half(acc[mf][0][r]);
                H[(size_t)gr * M + col0 + wn + 16 + l15] = __float2half(acc[mf][1][r]);
            }
        }

    // fused alpha epilogue (fp32 accumulators)
    int hw = (col0 + wn) / CH;
    int cb = (col0 + wn) % CH;
    float vs0 = a_src[hw * CH + cb + l15];
    float vs1 = a_src[hw * CH + cb + 16 + l15];
    float vd0 = a_dst[hw * CH + cb + l15];
    float vd1 = a_dst[hw * CH + cb + 16 + l15];

    #pragma unroll
    for (int mf = 0; mf < 4; ++mf)
        #pragma unroll
        for (int r = 0; r < 4; ++r) {
            float ss = acc[mf][0][r] * vs0 + acc[mf][1][r] * vs1;
            float sd = acc[mf][0][r] * vd0 + acc[mf][1][r] * vd1;
            #pragma unroll
            for (int o = 1; o < 16; o <<= 1) {
                ss += __shfl_xor(ss, o);
                sd += __shfl_xor(sd, o);
            }
            if (l15 == 0) {
                int ri = wm + mf * 16 + l4 * 4 + r;
                if constexpr (CH == 32) {
                    int gr = row0 + ri;
                    if (gr < n) {
                        asrc[(size_t)gr * 4 + hw] = ss;
                        adst[(size_t)gr * 4 + hw] = sd;
                    }
                } else {
                    scrf[((wid & 1) * 128 + ri) * 2 + 0] = ss;
                    scrf[((wid & 1) * 128 + ri) * 2 + 1] = sd;
                }
            }
        }
    if constexpr (CH == 64) {
        __syncthreads();
        if (tid < 128) {
            int gr = row0 + tid;
            if (gr < n) {
                int head = col0 / 64;
                asrc[(size_t)gr * 4 + head] = scrf[tid * 2 + 0] + scrf[(128 + tid) * 2 + 0];
                adst[(size_t)gr * 4 + head] = scrf[tid * 2 + 1] + scrf[(128 + tid) * 2 + 1];
            }
        }
    }
}

// ---------------- segment softmax + weighted aggregation ----------------
// One wave per dst node; softmax without max subtraction (shift-invariant,
// logits bounded, fp32-safe). Phase A stages p (SoA pad-66) + src in
// wave-private LDS; phase B gathers fp16 h rows with 8B loads, fp32 accum.
// Layers 1/2 (!MEAN) write fp16 (feeds next GEMM); layer 3 writes fp32 d_out.

template <int CPL, bool MEAN, int LAYER>
__global__ __launch_bounds__(256) void aggregate_kernel(
    const __half* __restrict__ h, const float* __restrict__ asrc,
    const float* __restrict__ adst, const int* __restrict__ csr_src,
    const int* __restrict__ row_ptr, const float* __restrict__ bias,
    void* __restrict__ out_, int n) {
    __shared__ float lds[4][332];
    int wid = threadIdx.x >> 6;
    int lane = threadIdx.x & 63;
    int node = blockIdx.x * 4 + wid;
    if (node >= n) return;
    float* Wp = lds[wid];
    int* Ws = (int*)&lds[wid][264];
    int start = row_ptr[node];
    int end = row_ptr[node + 1];
    float4 ad = *(const float4*)&adst[(size_t)node * 4];

    int l32, head, j_off;
    if constexpr (CPL == 2) {
        l32 = lane & 31; head = l32 >> 3; j_off = lane >> 5;
    } else {
        l32 = lane; head = lane >> 4; j_off = 0;
    }
    int hoff = head * 66;

    float acc0 = 0.f, acc1 = 0.f, acc2 = 0.f, acc3 = 0.f, pw = 0.f;

    for (int base = start; base < end; base += 64) {
        int cnt = end - base;
        if (cnt > 64) cnt = 64;
        int s = 0;
        float4 pv = {0.f, 0.f, 0.f, 0.f};
        if (lane < cnt) {
            s = csr_src[base + lane];
            float4 a = *(const float4*)&asrc[(size_t)s * 4];
            float e0 = a.x + ad.x; e0 = (e0 > 0.f) ? e0 : 0.2f * e0;
            float e1 = a.y + ad.y; e1 = (e1 > 0.f) ? e1 : 0.2f * e1;
            float e2 = a.z + ad.z; e2 = (e2 > 0.f) ? e2 : 0.2f * e2;
            float e3 = a.w + ad.w; e3 = (e3 > 0.f) ? e3 : 0.2f * e3;
            pv.x = __expf(e0); pv.y = __expf(e1); pv.z = __expf(e2); pv.w = __expf(e3);
        }
        Wp[0 * 66 + lane] = pv.x;
        Wp[1 * 66 + lane] = pv.y;
        Wp[2 * 66 + lane] = pv.z;
        Wp[3 * 66 + lane] = pv.w;
        Ws[lane] = s;
        __builtin_amdgcn_wave_barrier();
        asm volatile("" ::: "memory");
        if constexpr (CPL == 2) {
            #pragma unroll 4
            for (int jj = 0; jj < cnt; jj += 2) {
                int j = jj + j_off;
                float w = Wp[hoff + j];
                int s2 = Ws[j];
                float2 raw = *(const float2*)(h + (size_t)s2 * 128 + l32 * 4);
                __half2 p01 = ((const __half2*)&raw)[0];
                __half2 p23 = ((const __half2*)&raw)[1];
                float2 f01 = __half22float2(p01);
                float2 f23 = __half22float2(p23);
                acc0 += w * f01.x;
                acc1 += w * f01.y;
                acc2 += w * f23.x;
                acc3 += w * f23.y;
                pw += w;
            }
        } else {
            #pragma unroll 4
            for (int j = 0; j < cnt; ++j) {
                float w = Wp[hoff + j];
                int s2 = Ws[j];
                float2 raw = *(const float2*)(h + (size_t)s2 * 256 + lane * 4);
                __half2 p01 = ((const __half2*)&raw)[0];
                __half2 p23 = ((const __half2*)&raw)[1];
                float2 f01 = __half22float2(p01);
                float2 f23 = __half22float2(p23);
                acc0 += w * f01.x;
                acc1 += w * f01.y;
                acc2 += w * f23.x;
                acc3 += w * f23.y;
                pw += w;
            }
        }
        __builtin_amdgcn_wave_barrier();
        asm volatile("" ::: "memory");
    }

    if constexpr (!MEAN) {
        acc0 += __shfl_xor(acc0, 32);
        acc1 += __shfl_xor(acc1, 32);
        acc2 += __shfl_xor(acc2, 32);
        acc3 += __shfl_xor(acc3, 32);
        pw += __shfl_xor(pw, 32);
        if (lane < 32) {
            float inv = 1.f / (pw + 1e-16f);
            float4 b = *(const float4*)&bias[l32 * 4];
            __half* out = (__half*)out_;
            __half2 ha = __floats2half2_rn(acc0 * inv + b.x, acc1 * inv + b.y);
            __half2 hb = __floats2half2_rn(acc2 * inv + b.z, acc3 * inv + b.w);
            uint2 st = {*(unsigned int*)&ha, *(unsigned int*)&hb};
            *(uint2*)&out[(size_t)node * 128 + l32 * 4] = st;
        }
    } else {
        float inv = 1.f / (pw + 1e-16f);
        float r0 = acc0 * inv, r1 = acc1 * inv, r2 = acc2 * inv, r3 = acc3 * inv;
        r0 += __shfl_xor(r0, 16); r0 += __shfl_xor(r0, 32);
        r1 += __shfl_xor(r1, 16); r1 += __shfl_xor(r1, 32);
        r2 += __shfl_xor(r2, 16); r2 += __shfl_xor(r2, 32);
        r3 += __shfl_xor(r3, 16); r3 += __shfl_xor(r3, 32);
        if (lane < 16) {
            float* out = (float*)out_;
            float4 b = *(const float4*)&bias[lane * 4];
            float4 o;
            o.x = 0.25f * r0 + b.x;
            o.y = 0.25f * r1 + b.y;
            o.z = 0.25f * r2 + b.z;
            o.w = 0.25f * r3 + b.w;
            *(float4*)&out[(size_t)node * 64 + lane * 4] = o;
        }
    }
}

// ---------------- launch ----------------

extern "C" void kernel_launch(void* const* d_in, const int* in_sizes, int n_in,
                              void* d_out, int out_size, void* d_ws, size_t ws_size,
                              hipStream_t stream) {
    const float* x = (const float*)d_in[0];
    const int* ei = (const int*)d_in[1];
    const int* src = ei;
    const int* dst = ei + NEDGES;
    const float* W1 = (const float*)d_in[2];
    const float* as1 = (const float*)d_in[3];
    const float* ad1 = (const float*)d_in[4];
    const float* b1 = (const float*)d_in[5];
    const float* W2 = (const float*)d_in[6];
    const float* as2 = (const float*)d_in[7];
    const float* ad2 = (const float*)d_in[8];
    const float* b2 = (const float*)d_in[9];
    const float* W3 = (const float*)d_in[10];
    const float* as3 = (const float*)d_in[11];
    const float* ad3 = (const float*)d_in[12];
    const float* b3 = (const float*)d_in[13];

    char* ws = (char*)d_ws;
    size_t off = 0;
    auto take = [&](size_t bytes) -> char* {
        char* p = ws + off;
        off = (off + bytes + 255) & ~(size_t)255;
        return p;
    };
    int* csr = (int*)take((size_t)NEDGES * 4);
    int* row_ptr = (int*)take((size_t)(NNODES + 1) * 4);
    int* counts = (int*)take((size_t)NNODES * 4);
    int* cursor = (int*)take((size_t)NNODES * 4);
    int* bsums = (int*)take(1024 * 4);
    float* asrc = (float*)take((size_t)NNODES * 4 * 4);
    float* adst = (float*)take((size_t)NNODES * 4 * 4);
    __half* hbuf = (__half*)take((size_t)NNODES * 256 * 2);
    __half* buf1h = (__half*)take((size_t)NNODES * 128 * 2);
    float* outp = (float*)d_out;

    int nbN = (NNODES + 255) / 256;
    int nbE = (NEDGES + 255) / 256;
    int gnodeAgg = (NNODES + 3) / 4;

    // CSR build (graph shared by all layers)
    zero_i32<<<nbN, 256, 0, stream>>>(counts, NNODES);
    hist_kernel<<<nbE, 256, 0, stream>>>(dst, counts, NEDGES);
    scan1_kernel<<<nbN, 256, 0, stream>>>(counts, row_ptr, bsums, NNODES);
    scan2_kernel<<<1, 256, 0, stream>>>(bsums, nbN);
    scan3_kernel<<<nbN, 256, 0, stream>>>(row_ptr, bsums, cursor, NNODES);
    fill_kernel<<<nbE, 256, 0, stream>>>(src, dst, row_ptr, cursor, csr, NEDGES);

    dim3 gA((NNODES + 127) / 128, 2);  // M=128
    dim3 gB((NNODES + 127) / 128, 4);  // M=256

    // layer 1 (A fp32 -> inline convert)
    gemm_mfma<32, true, 1><<<gA, 256, 0, stream>>>(x, W1, as1, ad1, hbuf, asrc, adst, NNODES, 128);
    aggregate_kernel<2, false, 1><<<gnodeAgg, 256, 0, stream>>>(hbuf, asrc, adst, csr, row_ptr, b1, buf1h, NNODES);

    // layer 2
    gemm_mfma<32, false, 2><<<gA, 256, 0, stream>>>(buf1h, W2, as2, ad2, hbuf, asrc, adst, NNODES, 128);
    aggregate_kernel<2, false, 2><<<gnodeAgg, 256, 0, stream>>>(hbuf, asrc, adst, csr, row_ptr, b2, buf1h, NNODES);

    // layer 3
    gemm_mfma<64, false, 3><<<gB, 256, 0, stream>>>(buf1h, W3, as3, ad3, hbuf, asrc, adst, NNODES, 256);
    aggregate_kernel<4, true, 3><<<gnodeAgg, 256, 0, stream>>>(hbuf, asrc, adst, csr, row_ptr, b3, outp, NNODES);
}

// Round 8
// 287.216 us; speedup vs baseline: 1.9230x; 1.0297x over previous
//
#include <hip/hip_runtime.h>
#include <hip/hip_fp16.h>
#include <math.h>

#define NNODES 50000
#define NEDGES 800000

typedef _Float16 half8 __attribute__((ext_vector_type(8)));
typedef float floatx4 __attribute__((ext_vector_type(4)));

// ---------------- CSR construction ----------------

__global__ void zero_i32(int* __restrict__ p, int n) {
    int i = blockIdx.x * 256 + threadIdx.x;
    if (i < n) p[i] = 0;
}

__global__ void hist_kernel(const int* __restrict__ dst, int* __restrict__ counts, int e) {
    int i = blockIdx.x * 256 + threadIdx.x;
    if (i < e) atomicAdd(&counts[dst[i]], 1);
}

__global__ void scan1_kernel(const int* __restrict__ counts, int* __restrict__ row_ptr,
                             int* __restrict__ bsums, int n) {
    __shared__ int s[256];
    int tid = threadIdx.x;
    int i = blockIdx.x * 256 + tid;
    int v = (i < n) ? counts[i] : 0;
    s[tid] = v;
    __syncthreads();
    #pragma unroll
    for (int o = 1; o < 256; o <<= 1) {
        int t = (tid >= o) ? s[tid - o] : 0;
        __syncthreads();
        s[tid] += t;
        __syncthreads();
    }
    if (i < n) row_ptr[i + 1] = s[tid];
    if (tid == 255) bsums[blockIdx.x] = s[255];
}

__global__ void scan2_kernel(int* __restrict__ bsums, int nb) {
    __shared__ int s[256];
    int tid = threadIdx.x;
    int v = (tid < nb) ? bsums[tid] : 0;
    s[tid] = v;
    __syncthreads();
    #pragma unroll
    for (int o = 1; o < 256; o <<= 1) {
        int t = (tid >= o) ? s[tid - o] : 0;
        __syncthreads();
        s[tid] += t;
        __syncthreads();
    }
    if (tid < nb) bsums[tid] = s[tid] - v;  // exclusive
}

__global__ void scan3_kernel(int* __restrict__ row_ptr, const int* __restrict__ bsums,
                             int* __restrict__ cursor, int n) {
    int i = blockIdx.x * 256 + threadIdx.x;
    if (i < n) {
        row_ptr[i + 1] += bsums[blockIdx.x];
        cursor[i] = 0;
    }
    if (i == 0) row_ptr[0] = 0;
}

__global__ void fill_kernel(const int* __restrict__ src, const int* __restrict__ dst,
                            const int* __restrict__ row_ptr, int* __restrict__ cursor,
                            int* __restrict__ csr_src, int e) {
    int i = blockIdx.x * 256 + threadIdx.x;
    if (i < e) {
        int d = dst[i];
        int pos = atomicAdd(&cursor[d], 1);
        csr_src[row_ptr[d] + pos] = src[i];
    }
}

// ---------------- MFMA GEMM + fused attention logits ----------------
// H[n][M] (fp16) = A[n][128] @ W[128][M], fp32 accumulate via
// v_mfma_f32_16x16x32_f16. Tile 128x64, whole K=128 in LDS, 4 waves.
// W transposed+converted during staging (k-pairs -> ds_write_b32).

template <int CH, bool AF32, int LAYER>
__global__ __launch_bounds__(256, 3) void gemm_mfma(const void* __restrict__ A_,
                                                    const float* __restrict__ Wf,
                                                    const float* __restrict__ a_src,
                                                    const float* __restrict__ a_dst,
                                                    __half* __restrict__ H,
                                                    float* __restrict__ asrc,
                                                    float* __restrict__ adst, int n, int M) {
    __shared__ __half As[128][136];   // pad 8 halfs: 272B rows -> 2-way banks
    __shared__ __half Ws[64][136];
    float* scrf = (float*)&As[0][0];  // CH64 overlay: [2][128][2] floats
    int tid = threadIdx.x;
    int row0 = blockIdx.x * 128;
    int col0 = blockIdx.y * 64;

    // stage A-tile: 128 rows x 128 k
    if constexpr (AF32) {
        const float* Af = (const float*)A_;
        #pragma unroll
        for (int it = 0; it < 8; ++it) {
            int flat = tid + it * 256;
            int r = flat >> 4;
            int kq = (flat & 15) * 8;
            int gr = row0 + r;
            float4 v0 = {0.f, 0.f, 0.f, 0.f}, v1 = {0.f, 0.f, 0.f, 0.f};
            if (gr < n) {
                v0 = *(const float4*)&Af[(size_t)gr * 128 + kq];
                v1 = *(const float4*)&Af[(size_t)gr * 128 + kq + 4];
            }
            __half2 h0 = __floats2half2_rn(v0.x, v0.y);
            __half2 h1 = __floats2half2_rn(v0.z, v0.w);
            __half2 h2 = __floats2half2_rn(v1.x, v1.y);
            __half2 h3 = __floats2half2_rn(v1.z, v1.w);
            uint4 st = {*(unsigned*)&h0, *(unsigned*)&h1, *(unsigned*)&h2, *(unsigned*)&h3};
            *(uint4*)&As[r][kq] = st;
        }
    } else {
        const __half* Ah = (const __half*)A_;
        #pragma unroll
        for (int it = 0; it < 8; ++it) {
            int flat = tid + it * 256;
            int r = flat >> 4;
            int kq = (flat & 15) * 8;
            int gr = row0 + r;
            float4 v = {0.f, 0.f, 0.f, 0.f};
            if (gr < n) v = *(const float4*)&Ah[(size_t)gr * 128 + kq];
            *(float4*)&As[r][kq] = v;
        }
    }
    // stage W-tile: transpose+convert; 2 k-rows x 4 cols per thread-iter,
    // k-pair -> one half2 (ds_write_b32) per col.
    #pragma unroll
    for (int it = 0; it < 4; ++it) {
        int flat = tid + it * 256;      // 0..1023
        int kp = flat >> 4;             // 0..63
        int c4 = (flat & 15) * 4;       // 0..60
        int k = kp * 2;
        float4 va = *(const float4*)&Wf[(size_t)k * M + col0 + c4];
        float4 vb = *(const float4*)&Wf[(size_t)(k + 1) * M + col0 + c4];
        *(__half2*)&Ws[c4 + 0][k] = __floats2half2_rn(va.x, vb.x);
        *(__half2*)&Ws[c4 + 1][k] = __floats2half2_rn(va.y, vb.y);
        *(__half2*)&Ws[c4 + 2][k] = __floats2half2_rn(va.z, vb.z);
        *(__half2*)&Ws[c4 + 3][k] = __floats2half2_rn(va.w, vb.w);
    }
    __syncthreads();

    int lane = tid & 63;
    int wid = tid >> 6;
    int wm = (wid >> 1) * 64;
    int wn = (wid & 1) * 32;
    int l15 = lane & 15;
    int l4 = lane >> 4;

    floatx4 acc[4][2];
    #pragma unroll
    for (int mf = 0; mf < 4; ++mf)
        #pragma unroll
        for (int nf = 0; nf < 2; ++nf) {
            floatx4 z = {0.f, 0.f, 0.f, 0.f};
            acc[mf][nf] = z;
        }

    #pragma unroll
    for (int ks = 0; ks < 4; ++ks) {
        int kb = ks * 32 + l4 * 8;
        half8 b0 = *(const half8*)&Ws[wn + l15][kb];
        half8 b1 = *(const half8*)&Ws[wn + 16 + l15][kb];
        #pragma unroll
        for (int mf = 0; mf < 4; ++mf) {
            half8 a = *(const half8*)&As[wm + mf * 16 + l15][kb];
            acc[mf][0] = __builtin_amdgcn_mfma_f32_16x16x32_f16(a, b0, acc[mf][0], 0, 0, 0);
            acc[mf][1] = __builtin_amdgcn_mfma_f32_16x16x32_f16(a, b1, acc[mf][1], 0, 0, 0);
        }
    }
    if constexpr (CH == 64) __syncthreads();

    // H store (fp16)
    #pragma unroll
    for (int mf = 0; mf < 4; ++mf)
        #pragma unroll
        for (int r = 0; r < 4; ++r) {
            int gr = row0 + wm + mf * 16 + l4 * 4 + r;
            if (gr < n) {
                H[(size_t)gr * M + col0 + wn + l15] = __float2half(acc[mf][0][r]);
                H[(size_t)gr * M + col0 + wn + 16 + l15] = __float2half(acc[mf][1][r]);
            }
        }

    // fused alpha epilogue (fp32 accumulators)
    int hw = (col0 + wn) / CH;
    int cb = (col0 + wn) % CH;
    float vs0 = a_src[hw * CH + cb + l15];
    float vs1 = a_src[hw * CH + cb + 16 + l15];
    float vd0 = a_dst[hw * CH + cb + l15];
    float vd1 = a_dst[hw * CH + cb + 16 + l15];

    #pragma unroll
    for (int mf = 0; mf < 4; ++mf)
        #pragma unroll
        for (int r = 0; r < 4; ++r) {
            float ss = acc[mf][0][r] * vs0 + acc[mf][1][r] * vs1;
            float sd = acc[mf][0][r] * vd0 + acc[mf][1][r] * vd1;
            #pragma unroll
            for (int o = 1; o < 16; o <<= 1) {
                ss += __shfl_xor(ss, o);
                sd += __shfl_xor(sd, o);
            }
            if (l15 == 0) {
                int ri = wm + mf * 16 + l4 * 4 + r;
                if constexpr (CH == 32) {
                    int gr = row0 + ri;
                    if (gr < n) {
                        asrc[(size_t)gr * 4 + hw] = ss;
                        adst[(size_t)gr * 4 + hw] = sd;
                    }
                } else {
                    scrf[((wid & 1) * 128 + ri) * 2 + 0] = ss;
                    scrf[((wid & 1) * 128 + ri) * 2 + 1] = sd;
                }
            }
        }
    if constexpr (CH == 64) {
        __syncthreads();
        if (tid < 128) {
            int gr = row0 + tid;
            if (gr < n) {
                int head = col0 / 64;
                asrc[(size_t)gr * 4 + head] = scrf[tid * 2 + 0] + scrf[(128 + tid) * 2 + 0];
                adst[(size_t)gr * 4 + head] = scrf[tid * 2 + 1] + scrf[(128 + tid) * 2 + 1];
            }
        }
    }
}

// ---------------- segment softmax + weighted aggregation ----------------
// One wave per dst node. Phase A zero-fills all 64 LDS slots then stages
// p (SoA pad-66) + src. Phase B: supersteps of 8 in-flight 8B gathers per
// lane-half (explicit register arrays -> deep MLP; tail slots have w=0 and
// gather h[0] which is L1-resident, so no guards needed).

template <int CPL, bool MEAN, int LAYER>
__global__ __launch_bounds__(256) void aggregate_kernel(
    const __half* __restrict__ h, const float* __restrict__ asrc,
    const float* __restrict__ adst, const int* __restrict__ csr_src,
    const int* __restrict__ row_ptr, const float* __restrict__ bias,
    void* __restrict__ out_, int n) {
    __shared__ float lds[4][332];
    int wid = threadIdx.x >> 6;
    int lane = threadIdx.x & 63;
    int node = blockIdx.x * 4 + wid;
    if (node >= n) return;
    float* Wp = lds[wid];
    int* Ws = (int*)&lds[wid][264];
    int start = row_ptr[node];
    int end = row_ptr[node + 1];
    float4 ad = *(const float4*)&adst[(size_t)node * 4];

    int l32, head, j_off;
    if constexpr (CPL == 2) {
        l32 = lane & 31; head = l32 >> 3; j_off = lane >> 5;
    } else {
        l32 = lane; head = lane >> 4; j_off = 0;
    }
    int hoff = head * 66;

    float acc0 = 0.f, acc1 = 0.f, acc2 = 0.f, acc3 = 0.f, pw = 0.f;

    for (int base = start; base < end; base += 64) {
        int cnt = end - base;
        if (cnt > 64) cnt = 64;
        // ---- phase A ----
        int s = 0;
        float4 pv = {0.f, 0.f, 0.f, 0.f};
        if (lane < cnt) {
            s = csr_src[base + lane];
            float4 a = *(const float4*)&asrc[(size_t)s * 4];
            float e0 = a.x + ad.x; e0 = (e0 > 0.f) ? e0 : 0.2f * e0;
            float e1 = a.y + ad.y; e1 = (e1 > 0.f) ? e1 : 0.2f * e1;
            float e2 = a.z + ad.z; e2 = (e2 > 0.f) ? e2 : 0.2f * e2;
            float e3 = a.w + ad.w; e3 = (e3 > 0.f) ? e3 : 0.2f * e3;
            pv.x = __expf(e0); pv.y = __expf(e1); pv.z = __expf(e2); pv.w = __expf(e3);
        }
        Wp[0 * 66 + lane] = pv.x;
        Wp[1 * 66 + lane] = pv.y;
        Wp[2 * 66 + lane] = pv.z;
        Wp[3 * 66 + lane] = pv.w;
        Ws[lane] = s;   // s==0 for tail lanes
        __builtin_amdgcn_wave_barrier();
        asm volatile("" ::: "memory");
        // ---- phase B: supersteps, 8 gathers in flight ----
        if constexpr (CPL == 2) {
            for (int jj = 0; jj < cnt; jj += 16) {
                float w[8]; int sa[8];
                #pragma unroll
                for (int u = 0; u < 8; ++u) {
                    int j = jj + 2 * u + j_off;   // <= 63 always
                    w[u] = Wp[hoff + j];
                    sa[u] = Ws[j];
                }
                float2 v[8];
                #pragma unroll
                for (int u = 0; u < 8; ++u)
                    v[u] = *(const float2*)(h + (size_t)sa[u] * 128 + l32 * 4);
                #pragma unroll
                for (int u = 0; u < 8; ++u) {
                    float2 f01 = __half22float2(((const __half2*)&v[u])[0]);
                    float2 f23 = __half22float2(((const __half2*)&v[u])[1]);
                    acc0 += w[u] * f01.x;
                    acc1 += w[u] * f01.y;
                    acc2 += w[u] * f23.x;
                    acc3 += w[u] * f23.y;
                    pw += w[u];
                }
            }
        } else {
            for (int jj = 0; jj < cnt; jj += 8) {
                float w[8]; int sa[8];
                #pragma unroll
                for (int u = 0; u < 8; ++u) {
                    int j = jj + u;               // <= 63 always
                    w[u] = Wp[hoff + j];
                    sa[u] = Ws[j];
                }
                float2 v[8];
                #pragma unroll
                for (int u = 0; u < 8; ++u)
                    v[u] = *(const float2*)(h + (size_t)sa[u] * 256 + lane * 4);
                #pragma unroll
                for (int u = 0; u < 8; ++u) {
                    float2 f01 = __half22float2(((const __half2*)&v[u])[0]);
                    float2 f23 = __half22float2(((const __half2*)&v[u])[1]);
                    acc0 += w[u] * f01.x;
                    acc1 += w[u] * f01.y;
                    acc2 += w[u] * f23.x;
                    acc3 += w[u] * f23.y;
                    pw += w[u];
                }
            }
        }
        __builtin_amdgcn_wave_barrier();
        asm volatile("" ::: "memory");
    }

    if constexpr (!MEAN) {
        acc0 += __shfl_xor(acc0, 32);
        acc1 += __shfl_xor(acc1, 32);
        acc2 += __shfl_xor(acc2, 32);
        acc3 += __shfl_xor(acc3, 32);
        pw += __shfl_xor(pw, 32);
        if (lane < 32) {
            float inv = 1.f / (pw + 1e-16f);
            float4 b = *(const float4*)&bias[l32 * 4];
            __half* out = (__half*)out_;
            __half2 ha = __floats2half2_rn(acc0 * inv + b.x, acc1 * inv + b.y);
            __half2 hb = __floats2half2_rn(acc2 * inv + b.z, acc3 * inv + b.w);
            uint2 st = {*(unsigned int*)&ha, *(unsigned int*)&hb};
            *(uint2*)&out[(size_t)node * 128 + l32 * 4] = st;
        }
    } else {
        float inv = 1.f / (pw + 1e-16f);
        float r0 = acc0 * inv, r1 = acc1 * inv, r2 = acc2 * inv, r3 = acc3 * inv;
        r0 += __shfl_xor(r0, 16); r0 += __shfl_xor(r0, 32);
        r1 += __shfl_xor(r1, 16); r1 += __shfl_xor(r1, 32);
        r2 += __shfl_xor(r2, 16); r2 += __shfl_xor(r2, 32);
        r3 += __shfl_xor(r3, 16); r3 += __shfl_xor(r3, 32);
        if (lane < 16) {
            float* out = (float*)out_;
            float4 b = *(const float4*)&bias[lane * 4];
            float4 o;
            o.x = 0.25f * r0 + b.x;
            o.y = 0.25f * r1 + b.y;
            o.z = 0.25f * r2 + b.z;
            o.w = 0.25f * r3 + b.w;
            *(float4*)&out[(size_t)node * 64 + lane * 4] = o;
        }
    }
}

// ---------------- launch ----------------

extern "C" void kernel_launch(void* const* d_in, const int* in_sizes, int n_in,
                              void* d_out, int out_size, void* d_ws, size_t ws_size,
                              hipStream_t stream) {
    const float* x = (const float*)d_in[0];
    const int* ei = (const int*)d_in[1];
    const int* src = ei;
    const int* dst = ei + NEDGES;
    const float* W1 = (const float*)d_in[2];
    const float* as1 = (const float*)d_in[3];
    const float* ad1 = (const float*)d_in[4];
    const float* b1 = (const float*)d_in[5];
    const float* W2 = (const float*)d_in[6];
    const float* as2 = (const float*)d_in[7];
    const float* ad2 = (const float*)d_in[8];
    const float* b2 = (const float*)d_in[9];
    const float* W3 = (const float*)d_in[10];
    const float* as3 = (const float*)d_in[11];
    const float* ad3 = (const float*)d_in[12];
    const float* b3 = (const float*)d_in[13];

    char* ws = (char*)d_ws;
    size_t off = 0;
    auto take = [&](size_t bytes) -> char* {
        char* p = ws + off;
        off = (off + bytes + 255) & ~(size_t)255;
        return p;
    };
    int* csr = (int*)take((size_t)NEDGES * 4);
    int* row_ptr = (int*)take((size_t)(NNODES + 1) * 4);
    int* counts = (int*)take((size_t)NNODES * 4);
    int* cursor = (int*)take((size_t)NNODES * 4);
    int* bsums = (int*)take(1024 * 4);
    float* asrc = (float*)take((size_t)NNODES * 4 * 4);
    float* adst = (float*)take((size_t)NNODES * 4 * 4);
    __half* hbuf = (__half*)take((size_t)NNODES * 256 * 2);
    __half* buf1h = (__half*)take((size_t)NNODES * 128 * 2);
    float* outp = (float*)d_out;

    int nbN = (NNODES + 255) / 256;
    int nbE = (NEDGES + 255) / 256;
    int gnodeAgg = (NNODES + 3) / 4;

    zero_i32<<<nbN, 256, 0, stream>>>(counts, NNODES);
    hist_kernel<<<nbE, 256, 0, stream>>>(dst, counts, NEDGES);
    scan1_kernel<<<nbN, 256, 0, stream>>>(counts, row_ptr, bsums, NNODES);
    scan2_kernel<<<1, 256, 0, stream>>>(bsums, nbN);
    scan3_kernel<<<nbN, 256, 0, stream>>>(row_ptr, bsums, cursor, NNODES);
    fill_kernel<<<nbE, 256, 0, stream>>>(src, dst, row_ptr, cursor, csr, NEDGES);

    dim3 gA((NNODES + 127) / 128, 2);  // M=128
    dim3 gB((NNODES + 127) / 128, 4);  // M=256

    gemm_mfma<32, true, 1><<<gA, 256, 0, stream>>>(x, W1, as1, ad1, hbuf, asrc, adst, NNODES, 128);
    aggregate_kernel<2, false, 1><<<gnodeAgg, 256, 0, stream>>>(hbuf, asrc, adst, csr, row_ptr, b1, buf1h, NNODES);

    gemm_mfma<32, false, 2><<<gA, 256, 0, stream>>>(buf1h, W2, as2, ad2, hbuf, asrc, adst, NNODES, 128);
    aggregate_kernel<2, false, 2><<<gnodeAgg, 256, 0, stream>>>(hbuf, asrc, adst, csr, row_ptr, b2, buf1h, NNODES);

    gemm_mfma<64, false, 3><<<gB, 256, 0, stream>>>(buf1h, W3, as3, ad3, hbuf, asrc, adst, NNODES, 256);
    aggregate_kernel<4, true, 3><<<gnodeAgg, 256, 0, stream>>>(hbuf, asrc, adst, csr, row_ptr, b3, outp, NNODES);
}